// Round 6
// baseline (314.658 us; speedup 1.0000x reference)
//
#include <hip/hip_runtime.h>
#include <hip/hip_bf16.h>
#include <math.h>

typedef __attribute__((ext_vector_type(8))) short frag8;   // 8 bf16 (4 VGPRs)
typedef __attribute__((ext_vector_type(4))) float f32x4;

// ---------------- device helpers ----------------
__device__ __forceinline__ float gelu_exact(float x) {
    return 0.5f * x * (1.0f + erff(x * 0.70710678118654752f));
}
// raw v_exp_f32 (2^x, flush-to-zero)
__device__ __forceinline__ float exp2_raw(float x) {
    return __builtin_amdgcn_exp2f(x);
}
// softplus via native exp2/log2: log(1+e^x) = log2(1+2^(x*log2e)) * ln2
__device__ __forceinline__ float softplus_f(float x) {
    float e = exp2_raw(x * 1.4426950408889634f);
    float sp = __log2f(1.0f + e) * 0.6931471805599453f;
    return (x > 20.0f) ? x : sp;
}
__device__ __forceinline__ float sigmoid_f(float x) {
    return 1.0f / (1.0f + __expf(-x));
}
__device__ __forceinline__ unsigned short bf16bits(float x) {
    __hip_bfloat16 h = __float2bfloat16(x);
    return *(unsigned short*)&h;
}
__device__ __forceinline__ float bf2f(unsigned short u) {
    unsigned int v = ((unsigned int)u) << 16;
    return __builtin_bit_cast(float, v);
}
// sum over the 16 lanes of each DPP row-of-16 — VALU-pipe only
__device__ __forceinline__ float row_sum16(float x) {
    int t;
    t = __builtin_amdgcn_update_dpp(0, __builtin_bit_cast(int, x), 0x128, 0xf, 0xf, true); // row_ror:8
    x += __builtin_bit_cast(float, t);
    t = __builtin_amdgcn_update_dpp(0, __builtin_bit_cast(int, x), 0x124, 0xf, 0xf, true); // row_ror:4
    x += __builtin_bit_cast(float, t);
    t = __builtin_amdgcn_update_dpp(0, __builtin_bit_cast(int, x), 0x122, 0xf, 0xf, true); // row_ror:2
    x += __builtin_bit_cast(float, t);
    t = __builtin_amdgcn_update_dpp(0, __builtin_bit_cast(int, x), 0x121, 0xf, 0xf, true); // row_ror:1
    x += __builtin_bit_cast(float, t);
    return x;
}

// ---- linear-recurrence scan compose step (Hillis-Steele, 64 lanes) ----
// (A,B) <- (A,B) ∘after (tA,tB)   where tA,tB come from earlier lanes via DPP.
// Composite of f_left(x)=tA·x+tB then f_cur(x)=A·x+B is (A·tA)x + (A·tB + B).
// Invalid/unmasked lanes receive identity (tA=1, tB=0) via old-value operand.
#define SCAN_STEP(A, Bq, ctrl, rmask)                                          \
    {                                                                          \
        int ta_ = __builtin_amdgcn_update_dpp(0x3f800000,                      \
                      __builtin_bit_cast(int, A), ctrl, rmask, 0xf, false);    \
        int tb_ = __builtin_amdgcn_update_dpp(0,                               \
                      __builtin_bit_cast(int, Bq), ctrl, rmask, 0xf, false);   \
        float fa_ = __builtin_bit_cast(float, ta_);                            \
        float fb_ = __builtin_bit_cast(float, tb_);                            \
        Bq = fmaf(A, fb_, Bq);                                                 \
        A  = A * fa_;                                                          \
    }

#define SCAN64(A, Bq)            \
    SCAN_STEP(A, Bq, 0x111, 0xf) \
    SCAN_STEP(A, Bq, 0x112, 0xf) \
    SCAN_STEP(A, Bq, 0x114, 0xf) \
    SCAN_STEP(A, Bq, 0x118, 0xf) \
    SCAN_STEP(A, Bq, 0x142, 0xa) \
    SCAN_STEP(A, Bq, 0x143, 0xc)

// one (d,s)-chain for the current chunk: scan, apply carry, update carry, acc y
#define SCHAIN(AcS, Bv, Cv, cr)                                                \
    {                                                                          \
        float A  = exp2_raw(dt_c * AcS);                                       \
        float Bq = du * Bv;                                                    \
        SCAN64(A, Bq)                                                          \
        float st = fmaf(A, cr, Bq);                                            \
        cr = __builtin_bit_cast(float,                                         \
             __builtin_amdgcn_readlane(__builtin_bit_cast(int, st), 63));      \
        yacc = fmaf(Cv, st, yacc);                                             \
    }

// -------- fp32->bf16 weight cvt + Acoef + l2 zero + zero xdt/BT/CT (both layers)
struct CvtArgs {
    const float* src[6];
    unsigned short* dst[6];
    int n4[6];
};
__global__ __launch_bounds__(256)
void cvt_all(CvtArgs a, int total4, const float* __restrict__ Alog,
             float* __restrict__ Ac, float* __restrict__ Z, int zquads, float* l2)
{
    int i = blockIdx.x * 256 + threadIdx.x;
    if (i >= total4) {
        int j = i - total4;
        if (j < 16384) {
            Ac[j] = -__expf(Alog[j]) * 1.4426950408889634f;
        } else {
            int z = j - 16384;
            if (z < zquads) {
                float4 zero = {0.f, 0.f, 0.f, 0.f};
                reinterpret_cast<float4*>(Z)[z] = zero;
            }
        }
        if (j == 0) *l2 = 0.0f;
        return;
    }
    int seg = 0;
    while (i >= a.n4[seg]) { i -= a.n4[seg]; seg++; }
    float4 v = reinterpret_cast<const float4*>(a.src[seg])[i];
    ushort4 o;
    o.x = bf16bits(v.x); o.y = bf16bits(v.y); o.z = bf16bits(v.z); o.w = bf16bits(v.w);
    reinterpret_cast<ushort4*>(a.dst[seg])[i] = o;
}

// ---------------- ipw GEMM (N=1024, K=256): u-half -> xzuT fp32 [b][d][t],
// ---------------- z-half -> silu(z) bf16 szT [b][d][t] ----------------
// BK=64: 2 K-chunks staged per barrier pair (half the syncs of BK=32)
__global__ __launch_bounds__(256)
void gemm_ipw(const unsigned short* __restrict__ A,
              const unsigned short* __restrict__ W,
              float* __restrict__ xzuT,
              unsigned short* __restrict__ szT)
{
    __shared__ __align__(16) unsigned short As[64][72];
    __shared__ __align__(16) unsigned short Bs[64][72];

    const int tid = threadIdx.x;
    const int wid = tid >> 6, lane = tid & 63;
    const int wm = (wid >> 1) * 32, wn = (wid & 1) * 32;
    const int m0 = blockIdx.y * 64, n0 = blockIdx.x * 64;
    const int lrow = lane & 15, quad = lane >> 4;
    const int K = 256;

    const int sm = tid >> 2;
    const int sk = (tid & 3) * 8;

    f32x4 acc[2][2] = {};

    for (int k0 = 0; k0 < K; k0 += 64) {
        float4 av0 = *reinterpret_cast<const float4*>(A + (size_t)(m0 + sm) * K + k0 + sk);
        float4 av1 = *reinterpret_cast<const float4*>(A + (size_t)(m0 + sm) * K + k0 + sk + 32);
        *reinterpret_cast<float4*>(&As[sm][sk]) = av0;
        *reinterpret_cast<float4*>(&As[sm][sk + 32]) = av1;
        float4 bv0 = *reinterpret_cast<const float4*>(W + (size_t)(n0 + sm) * K + k0 + sk);
        float4 bv1 = *reinterpret_cast<const float4*>(W + (size_t)(n0 + sm) * K + k0 + sk + 32);
        *reinterpret_cast<float4*>(&Bs[sm][sk]) = bv0;
        *reinterpret_cast<float4*>(&Bs[sm][sk + 32]) = bv1;
        __syncthreads();

        #pragma unroll
        for (int h = 0; h < 2; h++) {
            frag8 a0 = *reinterpret_cast<const frag8*>(&As[wm + lrow][h * 32 + quad * 8]);
            frag8 a1 = *reinterpret_cast<const frag8*>(&As[wm + 16 + lrow][h * 32 + quad * 8]);
            frag8 b0 = *reinterpret_cast<const frag8*>(&Bs[wn + lrow][h * 32 + quad * 8]);
            frag8 b1 = *reinterpret_cast<const frag8*>(&Bs[wn + 16 + lrow][h * 32 + quad * 8]);

            acc[0][0] = __builtin_amdgcn_mfma_f32_16x16x32_bf16(a0, b0, acc[0][0], 0, 0, 0);
            acc[0][1] = __builtin_amdgcn_mfma_f32_16x16x32_bf16(a0, b1, acc[0][1], 0, 0, 0);
            acc[1][0] = __builtin_amdgcn_mfma_f32_16x16x32_bf16(a1, b0, acc[1][0], 0, 0, 0);
            acc[1][1] = __builtin_amdgcn_mfma_f32_16x16x32_bf16(a1, b1, acc[1][1], 0, 0, 0);
        }
        __syncthreads();
    }

    const int bb = m0 >> 10;
    const int tb = m0 & 1023;
    #pragma unroll
    for (int mi = 0; mi < 2; mi++) {
        int t4 = tb + wm + mi * 16 + quad * 4;
        #pragma unroll
        for (int nj = 0; nj < 2; nj++) {
            int col = n0 + wn + nj * 16 + lrow;
            if (col < 512) {
                float4 o = { acc[mi][nj][0], acc[mi][nj][1], acc[mi][nj][2], acc[mi][nj][3] };
                *reinterpret_cast<float4*>(xzuT + ((size_t)(bb * 512 + col)) * 1024 + t4) = o;
            } else {
                int z = col - 512;
                ushort4 o;
                float v0 = acc[mi][nj][0], v1 = acc[mi][nj][1], v2 = acc[mi][nj][2], v3 = acc[mi][nj][3];
                o.x = bf16bits(v0 * sigmoid_f(v0));
                o.y = bf16bits(v1 * sigmoid_f(v1));
                o.z = bf16bits(v2 * sigmoid_f(v2));
                o.w = bf16bits(v3 * sigmoid_f(v3));
                *reinterpret_cast<ushort4*>(szT + ((size_t)(bb * 512 + z)) * 1024 + t4) = o;
            }
        }
    }
}

// ---------------- conv4+SiLU fused into xpw projection, K-split x4 --------------
// BK=64 staging (half the barriers); outputs via atomicAdd into zeroed xdt/BT/CT
__global__ __launch_bounds__(256)
void gemm_cat(const float* __restrict__ xzuT,
              const unsigned short* __restrict__ W,     // xpw: 48 x 512 bf16
              const float* __restrict__ cw, const float* __restrict__ cb,
              float* __restrict__ ucT,
              float* __restrict__ xdt, float* __restrict__ BT, float* __restrict__ CT)
{
    __shared__ __align__(16) unsigned short As[64][72];
    __shared__ __align__(16) unsigned short Bs[64][72];

    const int tid = threadIdx.x;
    const int wid = tid >> 6, lane = tid & 63;
    const int wm = (wid >> 1) * 32, wn = (wid & 1) * 32;
    const int kc = blockIdx.x;            // 0..3 (128-d chunk)
    const int m0 = blockIdx.y * 64;
    const int bb = m0 >> 10;
    const int tb = m0 & 1023;
    const int lrow = lane & 15, quad = lane >> 4;
    const int N = 48;

    const int sm = tid >> 2;
    const int sk = (tid & 3) * 8;

    f32x4 acc[2][2] = {};

    for (int k0 = 0; k0 < 128; k0 += 64) {
        #pragma unroll
        for (int p = 0; p < 4; p++) {
            int kk = (tid >> 4) + p * 16;
            int k  = kc * 128 + k0 + kk;
            int mq = tid & 15;
            int tg = tb + mq * 4;
            const float* rowp = xzuT + ((size_t)(bb * 512 + k)) * 1024;
            float4 cur = *reinterpret_cast<const float4*>(rowp + tg);
            float4 prev = {0.f, 0.f, 0.f, 0.f};
            if (tg != 0) prev = *reinterpret_cast<const float4*>(rowp + tg - 4);
            float4 cv = *reinterpret_cast<const float4*>(cw + k * 4);
            float cbv = cb[k];
            float o0 = cbv + cv.x*prev.y + cv.y*prev.z + cv.z*prev.w + cv.w*cur.x;
            float o1 = cbv + cv.x*prev.z + cv.y*prev.w + cv.z*cur.x  + cv.w*cur.y;
            float o2 = cbv + cv.x*prev.w + cv.y*cur.x  + cv.z*cur.y  + cv.w*cur.z;
            float o3 = cbv + cv.x*cur.x  + cv.y*cur.y  + cv.z*cur.z  + cv.w*cur.w;
            o0 *= sigmoid_f(o0); o1 *= sigmoid_f(o1);
            o2 *= sigmoid_f(o2); o3 *= sigmoid_f(o3);
            float4 uo = { o0, o1, o2, o3 };
            *reinterpret_cast<float4*>(ucT + ((size_t)(bb * 512 + k)) * 1024 + tg) = uo;
            As[mq * 4 + 0][kk] = bf16bits(o0);
            As[mq * 4 + 1][kk] = bf16bits(o1);
            As[mq * 4 + 2][kk] = bf16bits(o2);
            As[mq * 4 + 3][kk] = bf16bits(o3);
        }
        float4 bv0 = {0.f, 0.f, 0.f, 0.f};
        float4 bv1 = {0.f, 0.f, 0.f, 0.f};
        if (sm < N) {
            bv0 = *reinterpret_cast<const float4*>(W + (size_t)sm * 512 + kc * 128 + k0 + sk);
            bv1 = *reinterpret_cast<const float4*>(W + (size_t)sm * 512 + kc * 128 + k0 + sk + 32);
        }
        *reinterpret_cast<float4*>(&Bs[sm][sk]) = bv0;
        *reinterpret_cast<float4*>(&Bs[sm][sk + 32]) = bv1;
        __syncthreads();

        #pragma unroll
        for (int h = 0; h < 2; h++) {
            frag8 a0 = *reinterpret_cast<const frag8*>(&As[wm + lrow][h * 32 + quad * 8]);
            frag8 a1 = *reinterpret_cast<const frag8*>(&As[wm + 16 + lrow][h * 32 + quad * 8]);
            frag8 b0 = *reinterpret_cast<const frag8*>(&Bs[wn + lrow][h * 32 + quad * 8]);
            frag8 b1 = *reinterpret_cast<const frag8*>(&Bs[wn + 16 + lrow][h * 32 + quad * 8]);

            acc[0][0] = __builtin_amdgcn_mfma_f32_16x16x32_bf16(a0, b0, acc[0][0], 0, 0, 0);
            acc[0][1] = __builtin_amdgcn_mfma_f32_16x16x32_bf16(a0, b1, acc[0][1], 0, 0, 0);
            acc[1][0] = __builtin_amdgcn_mfma_f32_16x16x32_bf16(a1, b0, acc[1][0], 0, 0, 0);
            acc[1][1] = __builtin_amdgcn_mfma_f32_16x16x32_bf16(a1, b1, acc[1][1], 0, 0, 0);
        }
        __syncthreads();
    }

    #pragma unroll
    for (int mi = 0; mi < 2; mi++) {
        #pragma unroll
        for (int nj = 0; nj < 2; nj++) {
            int col = wn + nj * 16 + lrow;
            if (col >= N) continue;
            #pragma unroll
            for (int r = 0; r < 4; r++) {
                int trow = tb + wm + mi * 16 + quad * 4 + r;     // t within batch
                float v = acc[mi][nj][r];
                if (col < 16)
                    atomicAdd(&xdt[((size_t)(bb * 1024 + trow)) * 16 + col], v);
                else if (col < 32)
                    atomicAdd(&BT[((size_t)(bb * 16 + col - 16)) * 1024 + trow], v);
                else
                    atomicAdd(&CT[((size_t)(bb * 16 + col - 32)) * 1024 + trow], v);
            }
        }
    }
}

// ---------------- full-row GEMM (N=256), 512 threads / 8 waves ------------------
// BK=64 staging: halves barrier count (K=768: 24 vs 48)
__global__ __launch_bounds__(512)
void rowgemm(const unsigned short* __restrict__ A,
             const float* __restrict__ Af,
             const unsigned short* __restrict__ W,
             const float* __restrict__ bias,
             const float* res,
             const float* g1, const float* b1, int gelu1,
             const float* g2, const float* b2,
             float* outF, unsigned short* outB, float* l2out,
             const unsigned short* clsW, const float* clsB, float* clsOut,
             int K)
{
    __shared__ __align__(16) unsigned short As[16][72];
    __shared__ __align__(16) unsigned short Bs[256][72];
    __shared__ float red[8][16][2];
    __shared__ float sq[16];
    __shared__ __align__(16) unsigned short hb[16][264];

    const int tid = threadIdx.x;
    const int w = tid >> 6, lane = tid & 63;
    const int lrow = lane & 15, quad = lane >> 4;
    const int m0 = blockIdx.x * 16;

    f32x4 acc[2] = {};

    for (int k0 = 0; k0 < K; k0 += 64) {
        if (tid < 64) {
            int r_ = tid >> 2, c8 = (tid & 3) * 8;
            if (Af) {
                const float* src = Af + (size_t)(m0 + r_) * K + k0;
                float4 v0 = *reinterpret_cast<const float4*>(src + c8);
                float4 v1 = *reinterpret_cast<const float4*>(src + c8 + 4);
                float4 v2 = *reinterpret_cast<const float4*>(src + c8 + 32);
                float4 v3 = *reinterpret_cast<const float4*>(src + c8 + 36);
                unsigned short* dst = &As[r_][c8];
                dst[0] = bf16bits(v0.x); dst[1] = bf16bits(v0.y);
                dst[2] = bf16bits(v0.z); dst[3] = bf16bits(v0.w);
                dst[4] = bf16bits(v1.x); dst[5] = bf16bits(v1.y);
                dst[6] = bf16bits(v1.z); dst[7] = bf16bits(v1.w);
                unsigned short* dst2 = &As[r_][c8 + 32];
                dst2[0] = bf16bits(v2.x); dst2[1] = bf16bits(v2.y);
                dst2[2] = bf16bits(v2.z); dst2[3] = bf16bits(v2.w);
                dst2[4] = bf16bits(v3.x); dst2[5] = bf16bits(v3.y);
                dst2[6] = bf16bits(v3.z); dst2[7] = bf16bits(v3.w);
            } else {
                float4 av0 = *reinterpret_cast<const float4*>(A + (size_t)(m0 + r_) * K + k0 + c8);
                float4 av1 = *reinterpret_cast<const float4*>(A + (size_t)(m0 + r_) * K + k0 + c8 + 32);
                *reinterpret_cast<float4*>(&As[r_][c8]) = av0;
                *reinterpret_cast<float4*>(&As[r_][c8 + 32]) = av1;
            }
        }
        #pragma unroll
        for (int i = 0; i < 2; i++) {
            int n = (tid >> 2) + i * 128;
            int c8 = (tid & 3) * 8;
            float4 bv0 = *reinterpret_cast<const float4*>(W + (size_t)n * K + k0 + c8);
            float4 bv1 = *reinterpret_cast<const float4*>(W + (size_t)n * K + k0 + c8 + 32);
            *reinterpret_cast<float4*>(&Bs[n][c8]) = bv0;
            *reinterpret_cast<float4*>(&Bs[n][c8 + 32]) = bv1;
        }
        __syncthreads();
        #pragma unroll
        for (int h = 0; h < 2; h++) {
            frag8 a = *reinterpret_cast<const frag8*>(&As[lrow][h * 32 + quad * 8]);
            #pragma unroll
            for (int nj = 0; nj < 2; nj++) {
                frag8 b = *reinterpret_cast<const frag8*>(&Bs[w * 32 + nj * 16 + lrow][h * 32 + quad * 8]);
                acc[nj] = __builtin_amdgcn_mfma_f32_16x16x32_bf16(a, b, acc[nj], 0, 0, 0);
            }
        }
        __syncthreads();
    }

    float v[2][4];
    #pragma unroll
    for (int nj = 0; nj < 2; nj++) {
        int col = w * 32 + nj * 16 + lrow;
        #pragma unroll
        for (int r = 0; r < 4; r++) {
            int row = m0 + quad * 4 + r;
            float t = acc[nj][r];
            if (bias) t += bias[col];
            if (res) t += res[(size_t)row * 256 + col];
            v[nj][r] = t;
        }
    }

    if (g1) {
        #pragma unroll
        for (int r = 0; r < 4; r++) {
            float s1 = v[0][r] + v[1][r];
            float s2 = v[0][r]*v[0][r] + v[1][r]*v[1][r];
            s1 = row_sum16(s1); s2 = row_sum16(s2);
            if (lrow == 0) { red[w][quad * 4 + r][0] = s1; red[w][quad * 4 + r][1] = s2; }
        }
        __syncthreads();
        #pragma unroll
        for (int r = 0; r < 4; r++) {
            int rr = quad * 4 + r;
            float t1 = 0.f, t2 = 0.f;
            #pragma unroll
            for (int ww = 0; ww < 8; ww++) { t1 += red[ww][rr][0]; t2 += red[ww][rr][1]; }
            float mu = t1 * (1.0f / 256.0f);
            float var = t2 * (1.0f / 256.0f) - mu * mu;
            float rstd = rsqrtf(var + 1e-5f);
            #pragma unroll
            for (int nj = 0; nj < 2; nj++) {
                int col = w * 32 + nj * 16 + lrow;
                float t = (v[nj][r] - mu) * rstd * g1[col] + b1[col];
                if (gelu1) t = gelu_exact(t);
                v[nj][r] = t;
            }
        }
        __syncthreads();
    } else if (gelu1) {
        #pragma unroll
        for (int nj = 0; nj < 2; nj++)
            #pragma unroll
            for (int r = 0; r < 4; r++)
                v[nj][r] = gelu_exact(v[nj][r]);
    }

    if (outF) {
        #pragma unroll
        for (int nj = 0; nj < 2; nj++) {
            int col = w * 32 + nj * 16 + lrow;
            #pragma unroll
            for (int r = 0; r < 4; r++)
                outF[(size_t)(m0 + quad * 4 + r) * 256 + col] = v[nj][r];
        }
    }

    if (l2out) {
        #pragma unroll
        for (int r = 0; r < 4; r++) {
            float s2 = v[0][r]*v[0][r] + v[1][r]*v[1][r];
            s2 = row_sum16(s2);
            if (lrow == 0) red[w][quad * 4 + r][0] = s2;
        }
        __syncthreads();
        if (tid < 16) {
            float t = 0.f;
            #pragma unroll
            for (int ww = 0; ww < 8; ww++) t += red[ww][tid][0];
            sq[tid] = sqrtf(t);
        }
        __syncthreads();
        if (tid == 0) {
            float a = 0.f;
            #pragma unroll
            for (int i = 0; i < 16; i++) a += sq[i];
            atomicAdd(l2out, a * (0.01f / 4096.0f));
        }
    }

    if (g2) {
        __syncthreads();
        #pragma unroll
        for (int r = 0; r < 4; r++) {
            float s1 = v[0][r] + v[1][r];
            float s2 = v[0][r]*v[0][r] + v[1][r]*v[1][r];
            s1 = row_sum16(s1); s2 = row_sum16(s2);
            if (lrow == 0) { red[w][quad * 4 + r][0] = s1; red[w][quad * 4 + r][1] = s2; }
        }
        __syncthreads();
        #pragma unroll
        for (int r = 0; r < 4; r++) {
            int rr = quad * 4 + r;
            float t1 = 0.f, t2 = 0.f;
            #pragma unroll
            for (int ww = 0; ww < 8; ww++) { t1 += red[ww][rr][0]; t2 += red[ww][rr][1]; }
            float mu = t1 * (1.0f / 256.0f);
            float var = t2 * (1.0f / 256.0f) - mu * mu;
            float rstd = rsqrtf(var + 1e-5f);
            #pragma unroll
            for (int nj = 0; nj < 2; nj++) {
                int col = w * 32 + nj * 16 + lrow;
                outB[(size_t)(m0 + rr) * 256 + col] = bf16bits((v[nj][r] - mu) * rstd * g2[col] + b2[col]);
            }
        }
    } else if (outB) {
        #pragma unroll
        for (int nj = 0; nj < 2; nj++) {
            int col = w * 32 + nj * 16 + lrow;
            #pragma unroll
            for (int r = 0; r < 4; r++)
                outB[(size_t)(m0 + quad * 4 + r) * 256 + col] = bf16bits(v[nj][r]);
        }
    }

    // ---- fused cls GEMM: logits(16 x 128) = v(16 x 256) @ clsW(128 x 256)^T ----
    if (clsW) {
        #pragma unroll
        for (int nj = 0; nj < 2; nj++) {
            int col = w * 32 + nj * 16 + lrow;
            #pragma unroll
            for (int r = 0; r < 4; r++)
                hb[quad * 4 + r][col] = bf16bits(v[nj][r]);
        }
        __syncthreads();
        f32x4 cacc = {};
        #pragma unroll
        for (int k0 = 0; k0 < 256; k0 += 32) {
            frag8 a = *reinterpret_cast<const frag8*>(&hb[lrow][k0 + quad * 8]);
            frag8 b = *reinterpret_cast<const frag8*>(clsW + (size_t)(w * 16 + lrow) * 256 + k0 + quad * 8);
            cacc = __builtin_amdgcn_mfma_f32_16x16x32_bf16(a, b, cacc, 0, 0, 0);
        }
        int col = w * 16 + lrow;
        float cb = clsB[col];
        #pragma unroll
        for (int r = 0; r < 4; r++)
            clsOut[(size_t)(m0 + quad * 4 + r) * 128 + col] = cacc[r] + cb;
    }
}

// ---------------- selective scan, lane-parallel-in-t (DPP segmented scan) -------
// Wave w owns d = w&3 and s-group (w>>2)*4..+3. Per 64-t chunk: 6-step DPP
// compose scan of the linear recurrence st = dA*st + dt*u*B, chunk carry via
// v_readlane(63). y = sum_s C*st reduced across the 4 s-groups with LDS
// atomicAdd. No cross-wave combine, no phase-C correction pass (half the exps
// of the serial-lane version; log-depth instead of 1024-step dependency chain).
__global__ __launch_bounds__(1024)
void scan_chunked(const float* __restrict__ xdt,
                  const float* __restrict__ dtw, const float* __restrict__ dtb,
                  const float* __restrict__ ucT,
                  const float* __restrict__ BT, const float* __restrict__ CT,
                  const unsigned short* __restrict__ szT,
                  const float* __restrict__ Ac,
                  const float* __restrict__ Dp,
                  unsigned short* __restrict__ y)
{
    __shared__ __align__(16) float dltS[4][1032];
    __shared__ __align__(16) float ucS[4][1032];
    __shared__ __align__(16) float yl[4][1032];

    const int j = blockIdx.x;
    const int bid = (j & 7) * 64 + (j >> 3);     // XCD swizzle
    const int b = bid >> 7;
    const int d0 = (bid & 127) * 4;
    const int w = threadIdx.x >> 6;
    const int lane = threadIdx.x & 63;
    const int t = threadIdx.x;                   // 0..1023

    // zero the y accumulator
    #pragma unroll
    for (int dd = 0; dd < 4; dd++) yl[dd][t] = 0.0f;

    // ---- issue long-latency loads first: uc stage, xdt, sz ----
    {
        int dd = lane >> 4, tq = (lane & 15) * 4;
        float4 v = *reinterpret_cast<const float4*>(ucT + ((size_t)(b * 512 + d0 + dd)) * 1024 + w * 64 + tq);
        *reinterpret_cast<float4*>(&ucS[dd][w * 64 + tq]) = v;
    }
    const float* xr = xdt + ((size_t)(b * 1024) + t) * 16;
    float4 x0 = *reinterpret_cast<const float4*>(xr + 0);
    float4 x1 = *reinterpret_cast<const float4*>(xr + 4);
    float4 x2 = *reinterpret_cast<const float4*>(xr + 8);
    float4 x3 = *reinterpret_cast<const float4*>(xr + 12);
    unsigned short szr[4];
    #pragma unroll
    for (int dd = 0; dd < 4; dd++)
        szr[dd] = szT[((size_t)(b * 512 + d0 + dd)) * 1024 + t];

    // ---- front-end: compute dlt for own t (all 4 d) ----
    #pragma unroll
    for (int dd = 0; dd < 4; dd++) {
        const float* wt = dtw + (size_t)(d0 + dd) * 16;
        float a2 = dtb[d0 + dd]
            + x0.x * wt[0]  + x0.y * wt[1]  + x0.z * wt[2]  + x0.w * wt[3]
            + x1.x * wt[4]  + x1.y * wt[5]  + x1.z * wt[6]  + x1.w * wt[7]
            + x2.x * wt[8]  + x2.y * wt[9]  + x2.z * wt[10] + x2.w * wt[11]
            + x3.x * wt[12] + x3.y * wt[13] + x3.z * wt[14] + x3.w * wt[15];
        dltS[dd][t] = softplus_f(a2);
    }
    __syncthreads();                              // dlt/uc/yl visible to all

    // ---- phase A: 4 independent (d,s) chains per wave, lane = t-in-chunk ----
    const int dI = w & 3;
    const int sB = (w >> 2) * 4;
    const float A0c = Ac[(d0 + dI) * 16 + sB + 0];   // prescaled by log2(e)
    const float A1c = Ac[(d0 + dI) * 16 + sB + 1];
    const float A2c = Ac[(d0 + dI) * 16 + sB + 2];
    const float A3c = Ac[(d0 + dI) * 16 + sB + 3];
    const float* B0p = BT + ((size_t)(b * 16 + sB + 0)) * 1024;
    const float* B1p = BT + ((size_t)(b * 16 + sB + 1)) * 1024;
    const float* B2p = BT + ((size_t)(b * 16 + sB + 2)) * 1024;
    const float* B3p = BT + ((size_t)(b * 16 + sB + 3)) * 1024;
    const float* C0p = CT + ((size_t)(b * 16 + sB + 0)) * 1024;
    const float* C1p = CT + ((size_t)(b * 16 + sB + 1)) * 1024;
    const float* C2p = CT + ((size_t)(b * 16 + sB + 2)) * 1024;
    const float* C3p = CT + ((size_t)(b * 16 + sB + 3)) * 1024;

    float cr0 = 0.f, cr1 = 0.f, cr2 = 0.f, cr3 = 0.f;
    float dt_c = dltS[dI][lane];
    float uu_c = ucS[dI][lane];
    float Bv0 = B0p[lane], Bv1 = B1p[lane], Bv2 = B2p[lane], Bv3 = B3p[lane];
    float Cv0 = C0p[lane], Cv1 = C1p[lane], Cv2 = C2p[lane], Cv3 = C3p[lane];

    for (int c = 0; c < 16; ++c) {
        float dt_n = 0.f, uu_n = 0.f;
        float Bn0 = 0.f, Bn1 = 0.f, Bn2 = 0.f, Bn3 = 0.f;
        float Cn0 = 0.f, Cn1 = 0.f, Cn2 = 0.f, Cn3 = 0.f;
        if (c < 15) {
            int tn = (c + 1) * 64 + lane;
            dt_n = dltS[dI][tn]; uu_n = ucS[dI][tn];
            Bn0 = B0p[tn]; Bn1 = B1p[tn]; Bn2 = B2p[tn]; Bn3 = B3p[tn];
            Cn0 = C0p[tn]; Cn1 = C1p[tn]; Cn2 = C2p[tn]; Cn3 = C3p[tn];
        }
        float du = dt_c * uu_c;
        float yacc = 0.0f;
        SCHAIN(A0c, Bv0, Cv0, cr0)
        SCHAIN(A1c, Bv1, Cv1, cr1)
        SCHAIN(A2c, Bv2, Cv2, cr2)
        SCHAIN(A3c, Bv3, Cv3, cr3)
        atomicAdd(&yl[dI][c * 64 + lane], yacc);
        dt_c = dt_n; uu_c = uu_n;
        Bv0 = Bn0; Bv1 = Bn1; Bv2 = Bn2; Bv3 = Bn3;
        Cv0 = Cn0; Cv1 = Cn1; Cv2 = Cn2; Cv3 = Cn3;
    }
    __syncthreads();                              // all s-group partials in yl

    // ---- epilogue: own t, 4 d ----
    const size_t row = (size_t)b * 1024 + t;
    ushort4 yo;
    {
        float ut0 = ucS[0][t], ut1 = ucS[1][t], ut2 = ucS[2][t], ut3 = ucS[3][t];
        float y0 = (yl[0][t] + ut0 * Dp[d0 + 0]) * bf2f(szr[0]);
        float y1 = (yl[1][t] + ut1 * Dp[d0 + 1]) * bf2f(szr[1]);
        float y2 = (yl[2][t] + ut2 * Dp[d0 + 2]) * bf2f(szr[2]);
        float y3 = (yl[3][t] + ut3 * Dp[d0 + 3]) * bf2f(szr[3]);
        yo.x = bf16bits(y0); yo.y = bf16bits(y1);
        yo.z = bf16bits(y2); yo.w = bf16bits(y3);
    }
    *reinterpret_cast<ushort4*>(y + row * 512 + d0) = yo;
}

// ---------------- launcher ----------------
extern "C" void kernel_launch(void* const* d_in, const int* in_sizes, int n_in,
                              void* d_out, int out_size, void* d_ws, size_t ws_size,
                              hipStream_t stream)
{
    const float* x      = (const float*)d_in[0];
    const float* in_b   = (const float*)d_in[2];
    const float* ln_g   = (const float*)d_in[3];
    const float* ln_b   = (const float*)d_in[4];
    const float* blk_ng  = (const float*)d_in[5];
    const float* blk_nb  = (const float*)d_in[6];
    const float* blk_cw  = (const float*)d_in[8];
    const float* blk_cb  = (const float*)d_in[9];
    const float* blk_dtw = (const float*)d_in[11];
    const float* blk_dtb = (const float*)d_in[12];
    const float* blk_Alog= (const float*)d_in[13];
    const float* blk_D   = (const float*)d_in[14];
    const float* op_b   = (const float*)d_in[17];
    const float* cls_b  = (const float*)d_in[19];
    float* out = (float*)d_out;

    const int BL = 4096;
    float* ws = (float*)d_ws;
    float* h0   = ws;                         // 1,048,576
    float* xzuT = h0 + 1048576;               // 2,097,152  [b][d][t] fp32 (u pre-conv)
    float* ucT  = xzuT + 2097152;             // 2,097,152  [b][d][t]
    float* xdt  = ucT + 2097152;              // 131,072 (2 layers x 4096x16)
    float* BT   = xdt + 131072;               // 131,072 (2 layers x [b][s][t])
    float* CT   = BT + 131072;                // 131,072
    float* Ac   = CT + 131072;                // 16,384
    unsigned short* szT = (unsigned short*)(Ac + 16384);  // 2,097,152 bf16 [b][d][t]
    unsigned short* wb  = szT + 2097152;      // 1,130,496
    unsigned short* hnb = wb + 1130496;       // 1,048,576
    unsigned short* ybb = hnb + 1048576;      // 2,097,152
    unsigned short* h0b = hnb;
    unsigned short* in_wb  = wb;
    unsigned short* ipw_b  = wb + 196608;
    unsigned short* xpw_b  = wb + 720896;
    unsigned short* opw_b  = wb + 770048;
    unsigned short* op_wb  = wb + 1032192;
    unsigned short* cls_wb = wb + 1097728;

    CvtArgs ca;
    ca.src[0] = (const float*)d_in[1];  ca.dst[0] = in_wb;  ca.n4[0] = 196608 / 4;
    ca.src[1] = (const float*)d_in[7];  ca.dst[1] = ipw_b;  ca.n4[1] = 524288 / 4;
    ca.src[2] = (const float*)d_in[10]; ca.dst[2] = xpw_b;  ca.n4[2] = 49152 / 4;
    ca.src[3] = (const float*)d_in[15]; ca.dst[3] = opw_b;  ca.n4[3] = 262144 / 4;
    ca.src[4] = (const float*)d_in[16]; ca.dst[4] = op_wb;  ca.n4[4] = 65536 / 4;
    ca.src[5] = (const float*)d_in[18]; ca.dst[5] = cls_wb; ca.n4[5] = 32768 / 4;
    int total4 = 1130496 / 4;
    int zquads = 393216 / 4;                  // xdt+BT+CT (both layers, contiguous)
    int totalg = total4 + 16384 + zquads;
    cvt_all<<<(totalg + 255) / 256, 256, 0, stream>>>(ca, total4, blk_Alog, Ac,
                                                      xdt, zquads,
                                                      out + (size_t)BL * 128);

    // in_proj (A from fp32 x) + bias + LN + GELU -> h0 (fp32), + LN(layer0) -> hnb
    rowgemm<<<256, 512, 0, stream>>>(nullptr, x, in_wb, in_b, nullptr,
                                     ln_g, ln_b, 1,
                                     blk_ng, blk_nb,
                                     h0, hnb, nullptr,
                                     nullptr, nullptr, nullptr, 768);

    for (int l = 0; l < 2; l++) {
        const float* cw   = blk_cw  + (size_t)l * 512 * 4;
        const float* cb   = blk_cb  + l * 512;
        const float* dtw  = blk_dtw + (size_t)l * 512 * 16;
        const float* dtb  = blk_dtb + l * 512;
        const float* Dl   = blk_D   + l * 512;
        const unsigned short* ipwl = ipw_b + (size_t)l * 262144;
        const unsigned short* xpwl = xpw_b + (size_t)l * 24576;
        const unsigned short* opwl = opw_b + (size_t)l * 131072;
        float* xdtl = xdt + (size_t)l * 65536;
        float* BTl  = BT  + (size_t)l * 65536;
        float* CTl  = CT  + (size_t)l * 65536;

        // ipw GEMM: u -> xzuT fp32 [b][d][t]; z -> silu(z) bf16 szT [b][d][t]
        gemm_ipw<<<dim3(16, 64), 256, 0, stream>>>(hnb, ipwl, xzuT, szT);
        // fused conv + xpw projection (K-split x4): ucT + atomic xdt/BT/CT
        gemm_cat<<<dim3(4, 64), 256, 0, stream>>>(xzuT, xpwl, cw, cb, ucT, xdtl, BTl, CTl);
        // scan (computes dlt from xdt in-kernel) -> ybb
        scan_chunked<<<512, 1024, 0, stream>>>(xdtl, dtw, dtb, ucT, BTl, CTl, szT,
                                               Ac + (size_t)l * 8192, Dl, ybb);
        // h0 += ybb @ opw.T; layer0: +LN(layer1)->hnb; layer1: ->h0b bf16 only
        if (l == 0)
            rowgemm<<<256, 512, 0, stream>>>(ybb, nullptr, opwl, nullptr, h0,
                                             nullptr, nullptr, 0,
                                             blk_ng + 256, blk_nb + 256,
                                             h0, hnb, nullptr,
                                             nullptr, nullptr, nullptr, 512);
        else
            rowgemm<<<256, 512, 0, stream>>>(ybb, nullptr, opwl, nullptr, h0,
                                             nullptr, nullptr, 0,
                                             nullptr, nullptr,
                                             nullptr, h0b, nullptr,
                                             nullptr, nullptr, nullptr, 512);
    }

    // final: h2 = gelu(h0b @ op_w.T + op_b); fused L2 scalar + cls GEMM -> out
    rowgemm<<<256, 512, 0, stream>>>(h0b, nullptr, op_wb, op_b, nullptr,
                                     nullptr, nullptr, 1,
                                     nullptr, nullptr,
                                     nullptr, nullptr, out + (size_t)BL * 128,
                                     cls_wb, cls_b, out, 256);
}

// Round 7
// 286.795 us; speedup vs baseline: 1.0972x; 1.0972x over previous
//
#include <hip/hip_runtime.h>
#include <hip/hip_bf16.h>
#include <math.h>

typedef __attribute__((ext_vector_type(8))) short frag8;   // 8 bf16 (4 VGPRs)
typedef __attribute__((ext_vector_type(4))) float f32x4;

// ---------------- device helpers ----------------
__device__ __forceinline__ float gelu_exact(float x) {
    return 0.5f * x * (1.0f + erff(x * 0.70710678118654752f));
}
// raw v_exp_f32 (2^x, flush-to-zero)
__device__ __forceinline__ float exp2_raw(float x) {
    return __builtin_amdgcn_exp2f(x);
}
// softplus via native exp2/log2: log(1+e^x) = log2(1+2^(x*log2e)) * ln2
__device__ __forceinline__ float softplus_f(float x) {
    float e = exp2_raw(x * 1.4426950408889634f);
    float sp = __log2f(1.0f + e) * 0.6931471805599453f;
    return (x > 20.0f) ? x : sp;
}
__device__ __forceinline__ float sigmoid_f(float x) {
    return 1.0f / (1.0f + __expf(-x));
}
__device__ __forceinline__ unsigned short bf16bits(float x) {
    __hip_bfloat16 h = __float2bfloat16(x);
    return *(unsigned short*)&h;
}
__device__ __forceinline__ float bf2f(unsigned short u) {
    unsigned int v = ((unsigned int)u) << 16;
    return __builtin_bit_cast(float, v);
}
// sum over the 16 lanes of each DPP row-of-16 — VALU-pipe only
__device__ __forceinline__ float row_sum16(float x) {
    int t;
    t = __builtin_amdgcn_update_dpp(0, __builtin_bit_cast(int, x), 0x128, 0xf, 0xf, true); // row_ror:8
    x += __builtin_bit_cast(float, t);
    t = __builtin_amdgcn_update_dpp(0, __builtin_bit_cast(int, x), 0x124, 0xf, 0xf, true); // row_ror:4
    x += __builtin_bit_cast(float, t);
    t = __builtin_amdgcn_update_dpp(0, __builtin_bit_cast(int, x), 0x122, 0xf, 0xf, true); // row_ror:2
    x += __builtin_bit_cast(float, t);
    t = __builtin_amdgcn_update_dpp(0, __builtin_bit_cast(int, x), 0x121, 0xf, 0xf, true); // row_ror:1
    x += __builtin_bit_cast(float, t);
    return x;
}
// inclusive prefix sum over the full 64-lane wave (DPP, VALU-pipe only)
__device__ __forceinline__ float prefix_sum64(float x) {
    int t;
    t = __builtin_amdgcn_update_dpp(0, __builtin_bit_cast(int, x), 0x111, 0xf, 0xf, true); // row_shr:1
    x += __builtin_bit_cast(float, t);
    t = __builtin_amdgcn_update_dpp(0, __builtin_bit_cast(int, x), 0x112, 0xf, 0xf, true); // row_shr:2
    x += __builtin_bit_cast(float, t);
    t = __builtin_amdgcn_update_dpp(0, __builtin_bit_cast(int, x), 0x114, 0xf, 0xf, true); // row_shr:4
    x += __builtin_bit_cast(float, t);
    t = __builtin_amdgcn_update_dpp(0, __builtin_bit_cast(int, x), 0x118, 0xf, 0xf, true); // row_shr:8
    x += __builtin_bit_cast(float, t);
    t = __builtin_amdgcn_update_dpp(0, __builtin_bit_cast(int, x), 0x142, 0xa, 0xf, true); // row_bcast:15
    x += __builtin_bit_cast(float, t);
    t = __builtin_amdgcn_update_dpp(0, __builtin_bit_cast(int, x), 0x143, 0xc, 0xf, true); // row_bcast:31
    x += __builtin_bit_cast(float, t);
    return x;
}

// -------- fp32->bf16 weight cvt + Acoef + l2 zero + zero xdt/BT/CT (both layers)
struct CvtArgs {
    const float* src[6];
    unsigned short* dst[6];
    int n4[6];
};
__global__ __launch_bounds__(256)
void cvt_all(CvtArgs a, int total4, const float* __restrict__ Alog,
             float* __restrict__ Ac, float* __restrict__ Z, int zquads, float* l2)
{
    int i = blockIdx.x * 256 + threadIdx.x;
    if (i >= total4) {
        int j = i - total4;
        if (j < 16384) {
            Ac[j] = -__expf(Alog[j]) * 1.4426950408889634f;
        } else {
            int z = j - 16384;
            if (z < zquads) {
                float4 zero = {0.f, 0.f, 0.f, 0.f};
                reinterpret_cast<float4*>(Z)[z] = zero;
            }
        }
        if (j == 0) *l2 = 0.0f;
        return;
    }
    int seg = 0;
    while (i >= a.n4[seg]) { i -= a.n4[seg]; seg++; }
    float4 v = reinterpret_cast<const float4*>(a.src[seg])[i];
    ushort4 o;
    o.x = bf16bits(v.x); o.y = bf16bits(v.y); o.z = bf16bits(v.z); o.w = bf16bits(v.w);
    reinterpret_cast<ushort4*>(a.dst[seg])[i] = o;
}

// ---------------- ipw GEMM (N=1024, K=256): u-half -> xzuT fp32 [b][d][t],
// ---------------- z-half -> silu(z) bf16 szT [b][d][t] ----------------
// BK=64: 2 K-chunks staged per barrier pair (half the syncs of BK=32)
__global__ __launch_bounds__(256)
void gemm_ipw(const unsigned short* __restrict__ A,
              const unsigned short* __restrict__ W,
              float* __restrict__ xzuT,
              unsigned short* __restrict__ szT)
{
    __shared__ __align__(16) unsigned short As[64][72];
    __shared__ __align__(16) unsigned short Bs[64][72];

    const int tid = threadIdx.x;
    const int wid = tid >> 6, lane = tid & 63;
    const int wm = (wid >> 1) * 32, wn = (wid & 1) * 32;
    const int m0 = blockIdx.y * 64, n0 = blockIdx.x * 64;
    const int lrow = lane & 15, quad = lane >> 4;
    const int K = 256;

    const int sm = tid >> 2;
    const int sk = (tid & 3) * 8;

    f32x4 acc[2][2] = {};

    for (int k0 = 0; k0 < K; k0 += 64) {
        float4 av0 = *reinterpret_cast<const float4*>(A + (size_t)(m0 + sm) * K + k0 + sk);
        float4 av1 = *reinterpret_cast<const float4*>(A + (size_t)(m0 + sm) * K + k0 + sk + 32);
        *reinterpret_cast<float4*>(&As[sm][sk]) = av0;
        *reinterpret_cast<float4*>(&As[sm][sk + 32]) = av1;
        float4 bv0 = *reinterpret_cast<const float4*>(W + (size_t)(n0 + sm) * K + k0 + sk);
        float4 bv1 = *reinterpret_cast<const float4*>(W + (size_t)(n0 + sm) * K + k0 + sk + 32);
        *reinterpret_cast<float4*>(&Bs[sm][sk]) = bv0;
        *reinterpret_cast<float4*>(&Bs[sm][sk + 32]) = bv1;
        __syncthreads();

        #pragma unroll
        for (int h = 0; h < 2; h++) {
            frag8 a0 = *reinterpret_cast<const frag8*>(&As[wm + lrow][h * 32 + quad * 8]);
            frag8 a1 = *reinterpret_cast<const frag8*>(&As[wm + 16 + lrow][h * 32 + quad * 8]);
            frag8 b0 = *reinterpret_cast<const frag8*>(&Bs[wn + lrow][h * 32 + quad * 8]);
            frag8 b1 = *reinterpret_cast<const frag8*>(&Bs[wn + 16 + lrow][h * 32 + quad * 8]);

            acc[0][0] = __builtin_amdgcn_mfma_f32_16x16x32_bf16(a0, b0, acc[0][0], 0, 0, 0);
            acc[0][1] = __builtin_amdgcn_mfma_f32_16x16x32_bf16(a0, b1, acc[0][1], 0, 0, 0);
            acc[1][0] = __builtin_amdgcn_mfma_f32_16x16x32_bf16(a1, b0, acc[1][0], 0, 0, 0);
            acc[1][1] = __builtin_amdgcn_mfma_f32_16x16x32_bf16(a1, b1, acc[1][1], 0, 0, 0);
        }
        __syncthreads();
    }

    const int bb = m0 >> 10;
    const int tb = m0 & 1023;
    #pragma unroll
    for (int mi = 0; mi < 2; mi++) {
        int t4 = tb + wm + mi * 16 + quad * 4;
        #pragma unroll
        for (int nj = 0; nj < 2; nj++) {
            int col = n0 + wn + nj * 16 + lrow;
            if (col < 512) {
                float4 o = { acc[mi][nj][0], acc[mi][nj][1], acc[mi][nj][2], acc[mi][nj][3] };
                *reinterpret_cast<float4*>(xzuT + ((size_t)(bb * 512 + col)) * 1024 + t4) = o;
            } else {
                int z = col - 512;
                ushort4 o;
                float v0 = acc[mi][nj][0], v1 = acc[mi][nj][1], v2 = acc[mi][nj][2], v3 = acc[mi][nj][3];
                o.x = bf16bits(v0 * sigmoid_f(v0));
                o.y = bf16bits(v1 * sigmoid_f(v1));
                o.z = bf16bits(v2 * sigmoid_f(v2));
                o.w = bf16bits(v3 * sigmoid_f(v3));
                *reinterpret_cast<ushort4*>(szT + ((size_t)(bb * 512 + z)) * 1024 + t4) = o;
            }
        }
    }
}

// ---------------- conv4+SiLU fused into xpw projection, K-split x8 --------------
// Grid (8,64) = 512 blocks -> 2 blocks/CU (was 1: every stall exposed).
// Each block handles one 64-d K-chunk in a single BK=64 stage.
__global__ __launch_bounds__(256)
void gemm_cat(const float* __restrict__ xzuT,
              const unsigned short* __restrict__ W,     // xpw: 48 x 512 bf16
              const float* __restrict__ cw, const float* __restrict__ cb,
              float* __restrict__ ucT,
              float* __restrict__ xdt, float* __restrict__ BT, float* __restrict__ CT)
{
    __shared__ __align__(16) unsigned short As[64][72];
    __shared__ __align__(16) unsigned short Bs[64][72];

    const int tid = threadIdx.x;
    const int wid = tid >> 6, lane = tid & 63;
    const int wm = (wid >> 1) * 32, wn = (wid & 1) * 32;
    const int kc = blockIdx.x;            // 0..7 (64-d chunk)
    const int m0 = blockIdx.y * 64;
    const int bb = m0 >> 10;
    const int tb = m0 & 1023;
    const int lrow = lane & 15, quad = lane >> 4;
    const int N = 48;

    const int sm = tid >> 2;
    const int sk = (tid & 3) * 8;

    f32x4 acc[2][2] = {};

    {
        #pragma unroll
        for (int p = 0; p < 4; p++) {
            int kk = (tid >> 4) + p * 16;
            int k  = kc * 64 + kk;
            int mq = tid & 15;
            int tg = tb + mq * 4;
            const float* rowp = xzuT + ((size_t)(bb * 512 + k)) * 1024;
            float4 cur = *reinterpret_cast<const float4*>(rowp + tg);
            float4 prev = {0.f, 0.f, 0.f, 0.f};
            if (tg != 0) prev = *reinterpret_cast<const float4*>(rowp + tg - 4);
            float4 cv = *reinterpret_cast<const float4*>(cw + k * 4);
            float cbv = cb[k];
            float o0 = cbv + cv.x*prev.y + cv.y*prev.z + cv.z*prev.w + cv.w*cur.x;
            float o1 = cbv + cv.x*prev.z + cv.y*prev.w + cv.z*cur.x  + cv.w*cur.y;
            float o2 = cbv + cv.x*prev.w + cv.y*cur.x  + cv.z*cur.y  + cv.w*cur.z;
            float o3 = cbv + cv.x*cur.x  + cv.y*cur.y  + cv.z*cur.z  + cv.w*cur.w;
            o0 *= sigmoid_f(o0); o1 *= sigmoid_f(o1);
            o2 *= sigmoid_f(o2); o3 *= sigmoid_f(o3);
            float4 uo = { o0, o1, o2, o3 };
            *reinterpret_cast<float4*>(ucT + ((size_t)(bb * 512 + k)) * 1024 + tg) = uo;
            As[mq * 4 + 0][kk] = bf16bits(o0);
            As[mq * 4 + 1][kk] = bf16bits(o1);
            As[mq * 4 + 2][kk] = bf16bits(o2);
            As[mq * 4 + 3][kk] = bf16bits(o3);
        }
        float4 bv0 = {0.f, 0.f, 0.f, 0.f};
        float4 bv1 = {0.f, 0.f, 0.f, 0.f};
        if (sm < N) {
            bv0 = *reinterpret_cast<const float4*>(W + (size_t)sm * 512 + kc * 64 + sk);
            bv1 = *reinterpret_cast<const float4*>(W + (size_t)sm * 512 + kc * 64 + sk + 32);
        }
        *reinterpret_cast<float4*>(&Bs[sm][sk]) = bv0;
        *reinterpret_cast<float4*>(&Bs[sm][sk + 32]) = bv1;
        __syncthreads();

        #pragma unroll
        for (int h = 0; h < 2; h++) {
            frag8 a0 = *reinterpret_cast<const frag8*>(&As[wm + lrow][h * 32 + quad * 8]);
            frag8 a1 = *reinterpret_cast<const frag8*>(&As[wm + 16 + lrow][h * 32 + quad * 8]);
            frag8 b0 = *reinterpret_cast<const frag8*>(&Bs[wn + lrow][h * 32 + quad * 8]);
            frag8 b1 = *reinterpret_cast<const frag8*>(&Bs[wn + 16 + lrow][h * 32 + quad * 8]);

            acc[0][0] = __builtin_amdgcn_mfma_f32_16x16x32_bf16(a0, b0, acc[0][0], 0, 0, 0);
            acc[0][1] = __builtin_amdgcn_mfma_f32_16x16x32_bf16(a0, b1, acc[0][1], 0, 0, 0);
            acc[1][0] = __builtin_amdgcn_mfma_f32_16x16x32_bf16(a1, b0, acc[1][0], 0, 0, 0);
            acc[1][1] = __builtin_amdgcn_mfma_f32_16x16x32_bf16(a1, b1, acc[1][1], 0, 0, 0);
        }
    }

    #pragma unroll
    for (int mi = 0; mi < 2; mi++) {
        #pragma unroll
        for (int nj = 0; nj < 2; nj++) {
            int col = wn + nj * 16 + lrow;
            if (col >= N) continue;
            #pragma unroll
            for (int r = 0; r < 4; r++) {
                int trow = tb + wm + mi * 16 + quad * 4 + r;     // t within batch
                float v = acc[mi][nj][r];
                if (col < 16)
                    atomicAdd(&xdt[((size_t)(bb * 1024 + trow)) * 16 + col], v);
                else if (col < 32)
                    atomicAdd(&BT[((size_t)(bb * 16 + col - 16)) * 1024 + trow], v);
                else
                    atomicAdd(&CT[((size_t)(bb * 16 + col - 32)) * 1024 + trow], v);
            }
        }
    }
}

// ---------------- full-row GEMM (N=256), 512 threads / 8 waves ------------------
// Register-staged pipeline: issue k+1 global loads right after the barrier so
// their latency hides under MFMA of k (1 block/CU -> no other block hides it).
__global__ __launch_bounds__(512)
void rowgemm(const unsigned short* __restrict__ A,
             const float* __restrict__ Af,
             const unsigned short* __restrict__ W,
             const float* __restrict__ bias,
             const float* res,
             const float* g1, const float* b1, int gelu1,
             const float* g2, const float* b2,
             float* outF, unsigned short* outB, float* l2out,
             const unsigned short* clsW, const float* clsB, float* clsOut,
             int K)
{
    __shared__ __align__(16) unsigned short As[16][72];
    __shared__ __align__(16) unsigned short Bs[256][72];
    __shared__ float red[8][16][2];
    __shared__ float sq[16];
    __shared__ __align__(16) unsigned short hb[16][264];

    const int tid = threadIdx.x;
    const int w = tid >> 6, lane = tid & 63;
    const int lrow = lane & 15, quad = lane >> 4;
    const int m0 = blockIdx.x * 16;
    const int r_ = tid >> 2, c8 = (tid & 3) * 8;
    const int nB0 = tid >> 2, nB1 = (tid >> 2) + 128;

    f32x4 acc[2] = {};
    float4 aR0, aR1, aR2, aR3;
    float4 bR0, bR1, bR2, bR3;

#define RG_LOAD(KOFF)                                                             \
    {                                                                             \
        if (tid < 64) {                                                           \
            if (Af) {                                                             \
                const float* src = Af + (size_t)(m0 + r_) * K + (KOFF);           \
                aR0 = *reinterpret_cast<const float4*>(src + c8);                 \
                aR1 = *reinterpret_cast<const float4*>(src + c8 + 4);             \
                aR2 = *reinterpret_cast<const float4*>(src + c8 + 32);            \
                aR3 = *reinterpret_cast<const float4*>(src + c8 + 36);            \
            } else {                                                              \
                aR0 = *reinterpret_cast<const float4*>(A + (size_t)(m0 + r_) * K + (KOFF) + c8);       \
                aR1 = *reinterpret_cast<const float4*>(A + (size_t)(m0 + r_) * K + (KOFF) + c8 + 32);  \
            }                                                                     \
        }                                                                         \
        bR0 = *reinterpret_cast<const float4*>(W + (size_t)nB0 * K + (KOFF) + c8);       \
        bR1 = *reinterpret_cast<const float4*>(W + (size_t)nB0 * K + (KOFF) + c8 + 32);  \
        bR2 = *reinterpret_cast<const float4*>(W + (size_t)nB1 * K + (KOFF) + c8);       \
        bR3 = *reinterpret_cast<const float4*>(W + (size_t)nB1 * K + (KOFF) + c8 + 32);  \
    }

#define RG_STORE()                                                                \
    {                                                                             \
        if (tid < 64) {                                                           \
            if (Af) {                                                             \
                unsigned short* dst = &As[r_][c8];                                \
                dst[0] = bf16bits(aR0.x); dst[1] = bf16bits(aR0.y);               \
                dst[2] = bf16bits(aR0.z); dst[3] = bf16bits(aR0.w);               \
                dst[4] = bf16bits(aR1.x); dst[5] = bf16bits(aR1.y);               \
                dst[6] = bf16bits(aR1.z); dst[7] = bf16bits(aR1.w);               \
                unsigned short* dst2 = &As[r_][c8 + 32];                          \
                dst2[0] = bf16bits(aR2.x); dst2[1] = bf16bits(aR2.y);             \
                dst2[2] = bf16bits(aR2.z); dst2[3] = bf16bits(aR2.w);             \
                dst2[4] = bf16bits(aR3.x); dst2[5] = bf16bits(aR3.y);             \
                dst2[6] = bf16bits(aR3.z); dst2[7] = bf16bits(aR3.w);             \
            } else {                                                              \
                *reinterpret_cast<float4*>(&As[r_][c8]) = aR0;                    \
                *reinterpret_cast<float4*>(&As[r_][c8 + 32]) = aR1;               \
            }                                                                     \
        }                                                                         \
        *reinterpret_cast<float4*>(&Bs[nB0][c8]) = bR0;                           \
        *reinterpret_cast<float4*>(&Bs[nB0][c8 + 32]) = bR1;                      \
        *reinterpret_cast<float4*>(&Bs[nB1][c8]) = bR2;                           \
        *reinterpret_cast<float4*>(&Bs[nB1][c8 + 32]) = bR3;                      \
    }

    RG_LOAD(0)
    for (int k0 = 0; k0 < K; k0 += 64) {
        RG_STORE()
        __syncthreads();
        if (k0 + 64 < K) RG_LOAD(k0 + 64)
        #pragma unroll
        for (int h = 0; h < 2; h++) {
            frag8 a = *reinterpret_cast<const frag8*>(&As[lrow][h * 32 + quad * 8]);
            #pragma unroll
            for (int nj = 0; nj < 2; nj++) {
                frag8 b = *reinterpret_cast<const frag8*>(&Bs[w * 32 + nj * 16 + lrow][h * 32 + quad * 8]);
                acc[nj] = __builtin_amdgcn_mfma_f32_16x16x32_bf16(a, b, acc[nj], 0, 0, 0);
            }
        }
        __syncthreads();
    }
#undef RG_LOAD
#undef RG_STORE

    float v[2][4];
    #pragma unroll
    for (int nj = 0; nj < 2; nj++) {
        int col = w * 32 + nj * 16 + lrow;
        #pragma unroll
        for (int r = 0; r < 4; r++) {
            int row = m0 + quad * 4 + r;
            float t = acc[nj][r];
            if (bias) t += bias[col];
            if (res) t += res[(size_t)row * 256 + col];
            v[nj][r] = t;
        }
    }

    if (g1) {
        #pragma unroll
        for (int r = 0; r < 4; r++) {
            float s1 = v[0][r] + v[1][r];
            float s2 = v[0][r]*v[0][r] + v[1][r]*v[1][r];
            s1 = row_sum16(s1); s2 = row_sum16(s2);
            if (lrow == 0) { red[w][quad * 4 + r][0] = s1; red[w][quad * 4 + r][1] = s2; }
        }
        __syncthreads();
        #pragma unroll
        for (int r = 0; r < 4; r++) {
            int rr = quad * 4 + r;
            float t1 = 0.f, t2 = 0.f;
            #pragma unroll
            for (int ww = 0; ww < 8; ww++) { t1 += red[ww][rr][0]; t2 += red[ww][rr][1]; }
            float mu = t1 * (1.0f / 256.0f);
            float var = t2 * (1.0f / 256.0f) - mu * mu;
            float rstd = rsqrtf(var + 1e-5f);
            #pragma unroll
            for (int nj = 0; nj < 2; nj++) {
                int col = w * 32 + nj * 16 + lrow;
                float t = (v[nj][r] - mu) * rstd * g1[col] + b1[col];
                if (gelu1) t = gelu_exact(t);
                v[nj][r] = t;
            }
        }
        __syncthreads();
    } else if (gelu1) {
        #pragma unroll
        for (int nj = 0; nj < 2; nj++)
            #pragma unroll
            for (int r = 0; r < 4; r++)
                v[nj][r] = gelu_exact(v[nj][r]);
    }

    if (outF) {
        #pragma unroll
        for (int nj = 0; nj < 2; nj++) {
            int col = w * 32 + nj * 16 + lrow;
            #pragma unroll
            for (int r = 0; r < 4; r++)
                outF[(size_t)(m0 + quad * 4 + r) * 256 + col] = v[nj][r];
        }
    }

    if (l2out) {
        #pragma unroll
        for (int r = 0; r < 4; r++) {
            float s2 = v[0][r]*v[0][r] + v[1][r]*v[1][r];
            s2 = row_sum16(s2);
            if (lrow == 0) red[w][quad * 4 + r][0] = s2;
        }
        __syncthreads();
        if (tid < 16) {
            float t = 0.f;
            #pragma unroll
            for (int ww = 0; ww < 8; ww++) t += red[ww][tid][0];
            sq[tid] = sqrtf(t);
        }
        __syncthreads();
        if (tid == 0) {
            float a = 0.f;
            #pragma unroll
            for (int i = 0; i < 16; i++) a += sq[i];
            atomicAdd(l2out, a * (0.01f / 4096.0f));
        }
    }

    if (g2) {
        __syncthreads();
        #pragma unroll
        for (int r = 0; r < 4; r++) {
            float s1 = v[0][r] + v[1][r];
            float s2 = v[0][r]*v[0][r] + v[1][r]*v[1][r];
            s1 = row_sum16(s1); s2 = row_sum16(s2);
            if (lrow == 0) { red[w][quad * 4 + r][0] = s1; red[w][quad * 4 + r][1] = s2; }
        }
        __syncthreads();
        #pragma unroll
        for (int r = 0; r < 4; r++) {
            int rr = quad * 4 + r;
            float t1 = 0.f, t2 = 0.f;
            #pragma unroll
            for (int ww = 0; ww < 8; ww++) { t1 += red[ww][rr][0]; t2 += red[ww][rr][1]; }
            float mu = t1 * (1.0f / 256.0f);
            float var = t2 * (1.0f / 256.0f) - mu * mu;
            float rstd = rsqrtf(var + 1e-5f);
            #pragma unroll
            for (int nj = 0; nj < 2; nj++) {
                int col = w * 32 + nj * 16 + lrow;
                outB[(size_t)(m0 + rr) * 256 + col] = bf16bits((v[nj][r] - mu) * rstd * g2[col] + b2[col]);
            }
        }
    } else if (outB) {
        #pragma unroll
        for (int nj = 0; nj < 2; nj++) {
            int col = w * 32 + nj * 16 + lrow;
            #pragma unroll
            for (int r = 0; r < 4; r++)
                outB[(size_t)(m0 + quad * 4 + r) * 256 + col] = bf16bits(v[nj][r]);
        }
    }

    // ---- fused cls GEMM: logits(16 x 128) = v(16 x 256) @ clsW(128 x 256)^T ----
    if (clsW) {
        #pragma unroll
        for (int nj = 0; nj < 2; nj++) {
            int col = w * 32 + nj * 16 + lrow;
            #pragma unroll
            for (int r = 0; r < 4; r++)
                hb[quad * 4 + r][col] = bf16bits(v[nj][r]);
        }
        __syncthreads();
        f32x4 cacc = {};
        #pragma unroll
        for (int k0 = 0; k0 < 256; k0 += 32) {
            frag8 a = *reinterpret_cast<const frag8*>(&hb[lrow][k0 + quad * 8]);
            frag8 b = *reinterpret_cast<const frag8*>(clsW + (size_t)(w * 16 + lrow) * 256 + k0 + quad * 8);
            cacc = __builtin_amdgcn_mfma_f32_16x16x32_bf16(a, b, cacc, 0, 0, 0);
        }
        int col = w * 16 + lrow;
        float cb = clsB[col];
        #pragma unroll
        for (int r = 0; r < 4; r++)
            clsOut[(size_t)(m0 + quad * 4 + r) * 128 + col] = cacc[r] + cb;
    }
}

// ---------------- chunked selective scan (round-5 serial structure) -------------
// Ac prescaled by log2(e); raw v_exp_f32. B/C prefetch deepened to 2 iterations
// (suspected exposed L2 latency at 1-deep; +8 VGPR, stays under the 64 cliff).
__global__ __launch_bounds__(1024)
void scan_chunked(const float* __restrict__ xdt,
                  const float* __restrict__ dtw, const float* __restrict__ dtb,
                  const float* __restrict__ ucT,
                  const float* __restrict__ BT, const float* __restrict__ CT,
                  const unsigned short* __restrict__ szT,
                  const float* __restrict__ Ac,
                  const float* __restrict__ Dp,
                  unsigned short* __restrict__ y)
{
    __shared__ float aprod_s[16][64];
    __shared__ float sfin_s[16][64];
    __shared__ float sin_w[16][64];
    __shared__ __align__(16) float ylocal[16][64][4];
    __shared__ __align__(16) float dltS[4][1032];
    __shared__ __align__(16) float ucS[4][1032];

    const int j = blockIdx.x;
    const int bid = (j & 7) * 64 + (j >> 3);     // XCD swizzle
    const int b = bid >> 7;
    const int d0 = (bid & 127) * 4;
    const int w = threadIdx.x >> 6;
    const int lane = threadIdx.x & 63;
    const int dsub = lane >> 4, s = lane & 15;
    const int d = d0 + dsub;
    const int t = w * 64 + lane;

    const float Acoef = Ac[d * 16 + s];          // already * log2(e)

    const float4* Bp = reinterpret_cast<const float4*>(BT + ((size_t)(b * 16 + s)) * 1024 + w * 64);
    const float4* Cp = reinterpret_cast<const float4*>(CT + ((size_t)(b * 16 + s)) * 1024 + w * 64);

    // ---- issue long-latency loads first: uc stage, xdt, B/C tiles 0+1, sz ----
    {
        int dd = lane >> 4, tq = (lane & 15) * 4;
        float4 v = *reinterpret_cast<const float4*>(ucT + ((size_t)(b * 512 + d0 + dd)) * 1024 + w * 64 + tq);
        *reinterpret_cast<float4*>(&ucS[dd][w * 64 + tq]) = v;
    }
    const float* xr = xdt + ((size_t)(b * 1024) + t) * 16;
    float4 x0 = *reinterpret_cast<const float4*>(xr + 0);
    float4 x1 = *reinterpret_cast<const float4*>(xr + 4);
    float4 x2 = *reinterpret_cast<const float4*>(xr + 8);
    float4 x3 = *reinterpret_cast<const float4*>(xr + 12);
    float4 B4 = Bp[0], C4 = Cp[0];
    float4 B5 = Bp[1], C5 = Cp[1];
    unsigned short szr[4];
    #pragma unroll
    for (int dd = 0; dd < 4; dd++)
        szr[dd] = szT[((size_t)(b * 512 + d0 + dd)) * 1024 + t];

    // ---- front-end: compute dlt for own chunk (lane = t) ----
    #pragma unroll
    for (int dd = 0; dd < 4; dd++) {
        const float* wt = dtw + (size_t)(d0 + dd) * 16;
        float a2 = dtb[d0 + dd]
            + x0.x * wt[0]  + x0.y * wt[1]  + x0.z * wt[2]  + x0.w * wt[3]
            + x1.x * wt[4]  + x1.y * wt[5]  + x1.z * wt[6]  + x1.w * wt[7]
            + x2.x * wt[8]  + x2.y * wt[9]  + x2.z * wt[10] + x2.w * wt[11]
            + x3.x * wt[12] + x3.y * wt[13] + x3.z * wt[14] + x3.w * wt[15];
        dltS[dd][t] = softplus_f(a2);
    }

    // ---- Phase A: local scan (B/C 2-deep prefetch; dlt/uc from LDS) ----
    float st = 0.0f, ap = 1.0f;
    #pragma unroll
    for (int q = 0; q < 16; q++) {
        float4 nB, nC;
        if (q < 14) { nB = Bp[q + 2]; nC = Cp[q + 2]; }
        float4 dt4 = *reinterpret_cast<const float4*>(&dltS[dsub][w * 64 + q * 4]);
        float4 ut4 = *reinterpret_cast<const float4*>(&ucS[dsub][w * 64 + q * 4]);
        const float* dtp = (const float*)&dt4;
        const float* utp = (const float*)&ut4;
        const float* Btp = (const float*)&B4;
        const float* Ctp = (const float*)&C4;
        #pragma unroll
        for (int jj = 0; jj < 4; jj++) {
            float dA = exp2_raw(dtp[jj] * Acoef);
            st = st * dA + dtp[jj] * utp[jj] * Btp[jj];
            ap *= dA;
            float part = row_sum16(st * Ctp[jj]);
            if (s == 0) ylocal[w][q * 4 + jj][dsub] = part;
        }
        B4 = B5; C4 = C5; B5 = nB; C5 = nC;
    }
    aprod_s[w][lane] = ap;
    sfin_s[w][lane] = st;
    __syncthreads();                                 // the only barrier

    // ---- decentralized combine ----
    {
        float pre = 0.0f;
        #pragma unroll
        for (int c = 0; c < 15; c++) {
            float apc = aprod_s[c][lane];
            float sfc = sfin_s[c][lane];
            float cand = sfc + apc * pre;
            pre = (c < w) ? cand : pre;
        }
        sin_w[w][lane] = pre;
    }

    // ---- Phase C: lane = t; correction via prefix sums + epilogue ----
    float cums[4];
    #pragma unroll
    for (int dd = 0; dd < 4; dd++)
        cums[dd] = dltS[dd][t];
    #pragma unroll
    for (int dd = 0; dd < 4; dd++) {
        float x = cums[dd];
        int tt;
        tt = __builtin_amdgcn_update_dpp(0, __builtin_bit_cast(int, x), 0x111, 0xf, 0xf, true);
        x += __builtin_bit_cast(float, tt);
        tt = __builtin_amdgcn_update_dpp(0, __builtin_bit_cast(int, x), 0x112, 0xf, 0xf, true);
        x += __builtin_bit_cast(float, tt);
        tt = __builtin_amdgcn_update_dpp(0, __builtin_bit_cast(int, x), 0x114, 0xf, 0xf, true);
        x += __builtin_bit_cast(float, tt);
        tt = __builtin_amdgcn_update_dpp(0, __builtin_bit_cast(int, x), 0x118, 0xf, 0xf, true);
        x += __builtin_bit_cast(float, tt);
        tt = __builtin_amdgcn_update_dpp(0, __builtin_bit_cast(int, x), 0x142, 0xa, 0xf, true);
        x += __builtin_bit_cast(float, tt);
        tt = __builtin_amdgcn_update_dpp(0, __builtin_bit_cast(int, x), 0x143, 0xc, 0xf, true);
        x += __builtin_bit_cast(float, tt);
        cums[dd] = x;
    }

    float4 yl = *reinterpret_cast<const float4*>(&ylocal[w][lane][0]);
    float acc[4] = { yl.x, yl.y, yl.z, yl.w };

    float Cs[4];
    #pragma unroll
    for (int jj = 0; jj < 4; jj++)
        Cs[jj] = CT[((size_t)(b * 16 + jj)) * 1024 + t];
    #pragma unroll
    for (int sq = 0; sq < 4; sq++) {
        float Csn[4];
        if (sq < 3) {
            #pragma unroll
            for (int jj = 0; jj < 4; jj++)
                Csn[jj] = CT[((size_t)(b * 16 + (sq + 1) * 4 + jj)) * 1024 + t];
        }
        #pragma unroll
        for (int dd = 0; dd < 4; dd++) {
            float4 sin4 = *reinterpret_cast<const float4*>(&sin_w[w][dd * 16 + sq * 4]);
            const float* sp = (const float*)&sin4;
            #pragma unroll
            for (int jj = 0; jj < 4; jj++) {
                float ac = Ac[(d0 + dd) * 16 + sq * 4 + jj];      // already * log2(e)
                acc[dd] += sp[jj] * Cs[jj] * exp2_raw(ac * cums[dd]);
            }
        }
        #pragma unroll
        for (int jj = 0; jj < 4; jj++) Cs[jj] = Csn[jj];
    }

    const size_t row = (size_t)b * 1024 + t;
    ushort4 yo;
    {
        float ut0 = ucS[0][t], ut1 = ucS[1][t], ut2 = ucS[2][t], ut3 = ucS[3][t];
        float y0 = (acc[0] + ut0 * Dp[d0 + 0]) * bf2f(szr[0]);
        float y1 = (acc[1] + ut1 * Dp[d0 + 1]) * bf2f(szr[1]);
        float y2 = (acc[2] + ut2 * Dp[d0 + 2]) * bf2f(szr[2]);
        float y3 = (acc[3] + ut3 * Dp[d0 + 3]) * bf2f(szr[3]);
        yo.x = bf16bits(y0); yo.y = bf16bits(y1);
        yo.z = bf16bits(y2); yo.w = bf16bits(y3);
    }
    *reinterpret_cast<ushort4*>(y + row * 512 + d0) = yo;
}

// ---------------- launcher ----------------
extern "C" void kernel_launch(void* const* d_in, const int* in_sizes, int n_in,
                              void* d_out, int out_size, void* d_ws, size_t ws_size,
                              hipStream_t stream)
{
    const float* x      = (const float*)d_in[0];
    const float* in_b   = (const float*)d_in[2];
    const float* ln_g   = (const float*)d_in[3];
    const float* ln_b   = (const float*)d_in[4];
    const float* blk_ng  = (const float*)d_in[5];
    const float* blk_nb  = (const float*)d_in[6];
    const float* blk_cw  = (const float*)d_in[8];
    const float* blk_cb  = (const float*)d_in[9];
    const float* blk_dtw = (const float*)d_in[11];
    const float* blk_dtb = (const float*)d_in[12];
    const float* blk_Alog= (const float*)d_in[13];
    const float* blk_D   = (const float*)d_in[14];
    const float* op_b   = (const float*)d_in[17];
    const float* cls_b  = (const float*)d_in[19];
    float* out = (float*)d_out;

    const int BL = 4096;
    float* ws = (float*)d_ws;
    float* h0   = ws;                         // 1,048,576
    float* xzuT = h0 + 1048576;               // 2,097,152  [b][d][t] fp32 (u pre-conv)
    float* ucT  = xzuT + 2097152;             // 2,097,152  [b][d][t]
    float* xdt  = ucT + 2097152;              // 131,072 (2 layers x 4096x16)
    float* BT   = xdt + 131072;               // 131,072 (2 layers x [b][s][t])
    float* CT   = BT + 131072;                // 131,072
    float* Ac   = CT + 131072;                // 16,384
    unsigned short* szT = (unsigned short*)(Ac + 16384);  // 2,097,152 bf16 [b][d][t]
    unsigned short* wb  = szT + 2097152;      // 1,130,496
    unsigned short* hnb = wb + 1130496;       // 1,048,576
    unsigned short* ybb = hnb + 1048576;      // 2,097,152
    unsigned short* h0b = hnb;
    unsigned short* in_wb  = wb;
    unsigned short* ipw_b  = wb + 196608;
    unsigned short* xpw_b  = wb + 720896;
    unsigned short* opw_b  = wb + 770048;
    unsigned short* op_wb  = wb + 1032192;
    unsigned short* cls_wb = wb + 1097728;

    CvtArgs ca;
    ca.src[0] = (const float*)d_in[1];  ca.dst[0] = in_wb;  ca.n4[0] = 196608 / 4;
    ca.src[1] = (const float*)d_in[7];  ca.dst[1] = ipw_b;  ca.n4[1] = 524288 / 4;
    ca.src[2] = (const float*)d_in[10]; ca.dst[2] = xpw_b;  ca.n4[2] = 49152 / 4;
    ca.src[3] = (const float*)d_in[15]; ca.dst[3] = opw_b;  ca.n4[3] = 262144 / 4;
    ca.src[4] = (const float*)d_in[16]; ca.dst[4] = op_wb;  ca.n4[4] = 65536 / 4;
    ca.src[5] = (const float*)d_in[18]; ca.dst[5] = cls_wb; ca.n4[5] = 32768 / 4;
    int total4 = 1130496 / 4;
    int zquads = 393216 / 4;                  // xdt+BT+CT (both layers, contiguous)
    int totalg = total4 + 16384 + zquads;
    cvt_all<<<(totalg + 255) / 256, 256, 0, stream>>>(ca, total4, blk_Alog, Ac,
                                                      xdt, zquads,
                                                      out + (size_t)BL * 128);

    // in_proj (A from fp32 x) + bias + LN + GELU -> h0 (fp32), + LN(layer0) -> hnb
    rowgemm<<<256, 512, 0, stream>>>(nullptr, x, in_wb, in_b, nullptr,
                                     ln_g, ln_b, 1,
                                     blk_ng, blk_nb,
                                     h0, hnb, nullptr,
                                     nullptr, nullptr, nullptr, 768);

    for (int l = 0; l < 2; l++) {
        const float* cw   = blk_cw  + (size_t)l * 512 * 4;
        const float* cb   = blk_cb  + l * 512;
        const float* dtw  = blk_dtw + (size_t)l * 512 * 16;
        const float* dtb  = blk_dtb + l * 512;
        const float* Dl   = blk_D   + l * 512;
        const unsigned short* ipwl = ipw_b + (size_t)l * 262144;
        const unsigned short* xpwl = xpw_b + (size_t)l * 24576;
        const unsigned short* opwl = opw_b + (size_t)l * 131072;
        float* xdtl = xdt + (size_t)l * 65536;
        float* BTl  = BT  + (size_t)l * 65536;
        float* CTl  = CT  + (size_t)l * 65536;

        // ipw GEMM: u -> xzuT fp32 [b][d][t]; z -> silu(z) bf16 szT [b][d][t]
        gemm_ipw<<<dim3(16, 64), 256, 0, stream>>>(hnb, ipwl, xzuT, szT);
        // fused conv + xpw projection (K-split x8 -> 512 blocks, 2/CU)
        gemm_cat<<<dim3(8, 64), 256, 0, stream>>>(xzuT, xpwl, cw, cb, ucT, xdtl, BTl, CTl);
        // scan (computes dlt from xdt in-kernel) -> ybb
        scan_chunked<<<512, 1024, 0, stream>>>(xdtl, dtw, dtb, ucT, BTl, CTl, szT,
                                               Ac + (size_t)l * 8192, Dl, ybb);
        // h0 += ybb @ opw.T; layer0: +LN(layer1)->hnb; layer1: ->h0b bf16 only
        if (l == 0)
            rowgemm<<<256, 512, 0, stream>>>(ybb, nullptr, opwl, nullptr, h0,
                                             nullptr, nullptr, 0,
                                             blk_ng + 256, blk_nb + 256,
                                             h0, hnb, nullptr,
                                             nullptr, nullptr, nullptr, 512);
        else
            rowgemm<<<256, 512, 0, stream>>>(ybb, nullptr, opwl, nullptr, h0,
                                             nullptr, nullptr, 0,
                                             nullptr, nullptr,
                                             nullptr, h0b, nullptr,
                                             nullptr, nullptr, nullptr, 512);
    }

    // final: h2 = gelu(h0b @ op_w.T + op_b); fused L2 scalar + cls GEMM -> out
    rowgemm<<<256, 512, 0, stream>>>(h0b, nullptr, op_wb, op_b, nullptr,
                                     nullptr, nullptr, 1,
                                     nullptr, nullptr,
                                     nullptr, nullptr, out + (size_t)BL * 128,
                                     cls_wb, cls_b, out, 256);
}

// Round 8
// 286.287 us; speedup vs baseline: 1.0991x; 1.0018x over previous
//
#include <hip/hip_runtime.h>
#include <hip/hip_bf16.h>
#include <math.h>

typedef __attribute__((ext_vector_type(8))) short frag8;   // 8 bf16 (4 VGPRs)
typedef __attribute__((ext_vector_type(4))) float f32x4;

// ---------------- device helpers ----------------
__device__ __forceinline__ float gelu_exact(float x) {
    return 0.5f * x * (1.0f + erff(x * 0.70710678118654752f));
}
// raw v_exp_f32 (2^x, flush-to-zero)
__device__ __forceinline__ float exp2_raw(float x) {
    return __builtin_amdgcn_exp2f(x);
}
// softplus via native exp2/log2: log(1+e^x) = log2(1+2^(x*log2e)) * ln2
__device__ __forceinline__ float softplus_f(float x) {
    float e = exp2_raw(x * 1.4426950408889634f);
    float sp = __log2f(1.0f + e) * 0.6931471805599453f;
    return (x > 20.0f) ? x : sp;
}
__device__ __forceinline__ float sigmoid_f(float x) {
    return 1.0f / (1.0f + __expf(-x));
}
__device__ __forceinline__ unsigned short bf16bits(float x) {
    __hip_bfloat16 h = __float2bfloat16(x);
    return *(unsigned short*)&h;
}
__device__ __forceinline__ float bf2f(unsigned short u) {
    unsigned int v = ((unsigned int)u) << 16;
    return __builtin_bit_cast(float, v);
}
// sum over the 16 lanes of each DPP row-of-16 — VALU-pipe only
__device__ __forceinline__ float row_sum16(float x) {
    int t;
    t = __builtin_amdgcn_update_dpp(0, __builtin_bit_cast(int, x), 0x128, 0xf, 0xf, true); // row_ror:8
    x += __builtin_bit_cast(float, t);
    t = __builtin_amdgcn_update_dpp(0, __builtin_bit_cast(int, x), 0x124, 0xf, 0xf, true); // row_ror:4
    x += __builtin_bit_cast(float, t);
    t = __builtin_amdgcn_update_dpp(0, __builtin_bit_cast(int, x), 0x122, 0xf, 0xf, true); // row_ror:2
    x += __builtin_bit_cast(float, t);
    t = __builtin_amdgcn_update_dpp(0, __builtin_bit_cast(int, x), 0x121, 0xf, 0xf, true); // row_ror:1
    x += __builtin_bit_cast(float, t);
    return x;
}
// inclusive prefix sum over the full 64-lane wave (DPP, VALU-pipe only)
__device__ __forceinline__ float prefix_sum64(float x) {
    int t;
    t = __builtin_amdgcn_update_dpp(0, __builtin_bit_cast(int, x), 0x111, 0xf, 0xf, true); // row_shr:1
    x += __builtin_bit_cast(float, t);
    t = __builtin_amdgcn_update_dpp(0, __builtin_bit_cast(int, x), 0x112, 0xf, 0xf, true); // row_shr:2
    x += __builtin_bit_cast(float, t);
    t = __builtin_amdgcn_update_dpp(0, __builtin_bit_cast(int, x), 0x114, 0xf, 0xf, true); // row_shr:4
    x += __builtin_bit_cast(float, t);
    t = __builtin_amdgcn_update_dpp(0, __builtin_bit_cast(int, x), 0x118, 0xf, 0xf, true); // row_shr:8
    x += __builtin_bit_cast(float, t);
    t = __builtin_amdgcn_update_dpp(0, __builtin_bit_cast(int, x), 0x142, 0xa, 0xf, true); // row_bcast:15
    x += __builtin_bit_cast(float, t);
    t = __builtin_amdgcn_update_dpp(0, __builtin_bit_cast(int, x), 0x143, 0xc, 0xf, true); // row_bcast:31
    x += __builtin_bit_cast(float, t);
    return x;
}

// -------- fp32->bf16 weight cvt + Acoef + l2 zero + zero xdt/BT/CT (both layers)
struct CvtArgs {
    const float* src[6];
    unsigned short* dst[6];
    int n4[6];
};
__global__ __launch_bounds__(256)
void cvt_all(CvtArgs a, int total4, const float* __restrict__ Alog,
             float* __restrict__ Ac, float* __restrict__ Z, int zquads, float* l2)
{
    int i = blockIdx.x * 256 + threadIdx.x;
    if (i >= total4) {
        int j = i - total4;
        if (j < 16384) {
            Ac[j] = -__expf(Alog[j]) * 1.4426950408889634f;
        } else {
            int z = j - 16384;
            if (z < zquads) {
                float4 zero = {0.f, 0.f, 0.f, 0.f};
                reinterpret_cast<float4*>(Z)[z] = zero;
            }
        }
        if (j == 0) *l2 = 0.0f;
        return;
    }
    int seg = 0;
    while (i >= a.n4[seg]) { i -= a.n4[seg]; seg++; }
    float4 v = reinterpret_cast<const float4*>(a.src[seg])[i];
    ushort4 o;
    o.x = bf16bits(v.x); o.y = bf16bits(v.y); o.z = bf16bits(v.z); o.w = bf16bits(v.w);
    reinterpret_cast<ushort4*>(a.dst[seg])[i] = o;
}

// ---------------- ipw GEMM (N=1024, K=256): u-half -> xzuT fp32 [b][d][t],
// ---------------- z-half -> silu(z) bf16 szT [b][d][t] ----------------
// BK=64: 2 K-chunks staged per barrier pair (half the syncs of BK=32)
__global__ __launch_bounds__(256)
void gemm_ipw(const unsigned short* __restrict__ A,
              const unsigned short* __restrict__ W,
              float* __restrict__ xzuT,
              unsigned short* __restrict__ szT)
{
    __shared__ __align__(16) unsigned short As[64][72];
    __shared__ __align__(16) unsigned short Bs[64][72];

    const int tid = threadIdx.x;
    const int wid = tid >> 6, lane = tid & 63;
    const int wm = (wid >> 1) * 32, wn = (wid & 1) * 32;
    const int m0 = blockIdx.y * 64, n0 = blockIdx.x * 64;
    const int lrow = lane & 15, quad = lane >> 4;
    const int K = 256;

    const int sm = tid >> 2;
    const int sk = (tid & 3) * 8;

    f32x4 acc[2][2] = {};

    for (int k0 = 0; k0 < K; k0 += 64) {
        float4 av0 = *reinterpret_cast<const float4*>(A + (size_t)(m0 + sm) * K + k0 + sk);
        float4 av1 = *reinterpret_cast<const float4*>(A + (size_t)(m0 + sm) * K + k0 + sk + 32);
        *reinterpret_cast<float4*>(&As[sm][sk]) = av0;
        *reinterpret_cast<float4*>(&As[sm][sk + 32]) = av1;
        float4 bv0 = *reinterpret_cast<const float4*>(W + (size_t)(n0 + sm) * K + k0 + sk);
        float4 bv1 = *reinterpret_cast<const float4*>(W + (size_t)(n0 + sm) * K + k0 + sk + 32);
        *reinterpret_cast<float4*>(&Bs[sm][sk]) = bv0;
        *reinterpret_cast<float4*>(&Bs[sm][sk + 32]) = bv1;
        __syncthreads();

        #pragma unroll
        for (int h = 0; h < 2; h++) {
            frag8 a0 = *reinterpret_cast<const frag8*>(&As[wm + lrow][h * 32 + quad * 8]);
            frag8 a1 = *reinterpret_cast<const frag8*>(&As[wm + 16 + lrow][h * 32 + quad * 8]);
            frag8 b0 = *reinterpret_cast<const frag8*>(&Bs[wn + lrow][h * 32 + quad * 8]);
            frag8 b1 = *reinterpret_cast<const frag8*>(&Bs[wn + 16 + lrow][h * 32 + quad * 8]);

            acc[0][0] = __builtin_amdgcn_mfma_f32_16x16x32_bf16(a0, b0, acc[0][0], 0, 0, 0);
            acc[0][1] = __builtin_amdgcn_mfma_f32_16x16x32_bf16(a0, b1, acc[0][1], 0, 0, 0);
            acc[1][0] = __builtin_amdgcn_mfma_f32_16x16x32_bf16(a1, b0, acc[1][0], 0, 0, 0);
            acc[1][1] = __builtin_amdgcn_mfma_f32_16x16x32_bf16(a1, b1, acc[1][1], 0, 0, 0);
        }
        __syncthreads();
    }

    const int bb = m0 >> 10;
    const int tb = m0 & 1023;
    #pragma unroll
    for (int mi = 0; mi < 2; mi++) {
        int t4 = tb + wm + mi * 16 + quad * 4;
        #pragma unroll
        for (int nj = 0; nj < 2; nj++) {
            int col = n0 + wn + nj * 16 + lrow;
            if (col < 512) {
                float4 o = { acc[mi][nj][0], acc[mi][nj][1], acc[mi][nj][2], acc[mi][nj][3] };
                *reinterpret_cast<float4*>(xzuT + ((size_t)(bb * 512 + col)) * 1024 + t4) = o;
            } else {
                int z = col - 512;
                ushort4 o;
                float v0 = acc[mi][nj][0], v1 = acc[mi][nj][1], v2 = acc[mi][nj][2], v3 = acc[mi][nj][3];
                o.x = bf16bits(v0 * sigmoid_f(v0));
                o.y = bf16bits(v1 * sigmoid_f(v1));
                o.z = bf16bits(v2 * sigmoid_f(v2));
                o.w = bf16bits(v3 * sigmoid_f(v3));
                *reinterpret_cast<ushort4*>(szT + ((size_t)(bb * 512 + z)) * 1024 + t4) = o;
            }
        }
    }
}

// ---------------- conv4+SiLU fused into xpw projection, K-split x4 --------------
// (round-5 form: K-split x8 + reg-staged rowgemm regressed −5.8 µs in round 7)
__global__ __launch_bounds__(256)
void gemm_cat(const float* __restrict__ xzuT,
              const unsigned short* __restrict__ W,     // xpw: 48 x 512 bf16
              const float* __restrict__ cw, const float* __restrict__ cb,
              float* __restrict__ ucT,
              float* __restrict__ xdt, float* __restrict__ BT, float* __restrict__ CT)
{
    __shared__ __align__(16) unsigned short As[64][72];
    __shared__ __align__(16) unsigned short Bs[64][72];

    const int tid = threadIdx.x;
    const int wid = tid >> 6, lane = tid & 63;
    const int wm = (wid >> 1) * 32, wn = (wid & 1) * 32;
    const int kc = blockIdx.x;            // 0..3 (128-d chunk)
    const int m0 = blockIdx.y * 64;
    const int bb = m0 >> 10;
    const int tb = m0 & 1023;
    const int lrow = lane & 15, quad = lane >> 4;
    const int N = 48;

    const int sm = tid >> 2;
    const int sk = (tid & 3) * 8;

    f32x4 acc[2][2] = {};

    for (int k0 = 0; k0 < 128; k0 += 64) {
        #pragma unroll
        for (int p = 0; p < 4; p++) {
            int kk = (tid >> 4) + p * 16;
            int k  = kc * 128 + k0 + kk;
            int mq = tid & 15;
            int tg = tb + mq * 4;
            const float* rowp = xzuT + ((size_t)(bb * 512 + k)) * 1024;
            float4 cur = *reinterpret_cast<const float4*>(rowp + tg);
            float4 prev = {0.f, 0.f, 0.f, 0.f};
            if (tg != 0) prev = *reinterpret_cast<const float4*>(rowp + tg - 4);
            float4 cv = *reinterpret_cast<const float4*>(cw + k * 4);
            float cbv = cb[k];
            float o0 = cbv + cv.x*prev.y + cv.y*prev.z + cv.z*prev.w + cv.w*cur.x;
            float o1 = cbv + cv.x*prev.z + cv.y*prev.w + cv.z*cur.x  + cv.w*cur.y;
            float o2 = cbv + cv.x*prev.w + cv.y*cur.x  + cv.z*cur.y  + cv.w*cur.z;
            float o3 = cbv + cv.x*cur.x  + cv.y*cur.y  + cv.z*cur.z  + cv.w*cur.w;
            o0 *= sigmoid_f(o0); o1 *= sigmoid_f(o1);
            o2 *= sigmoid_f(o2); o3 *= sigmoid_f(o3);
            float4 uo = { o0, o1, o2, o3 };
            *reinterpret_cast<float4*>(ucT + ((size_t)(bb * 512 + k)) * 1024 + tg) = uo;
            As[mq * 4 + 0][kk] = bf16bits(o0);
            As[mq * 4 + 1][kk] = bf16bits(o1);
            As[mq * 4 + 2][kk] = bf16bits(o2);
            As[mq * 4 + 3][kk] = bf16bits(o3);
        }
        float4 bv0 = {0.f, 0.f, 0.f, 0.f};
        float4 bv1 = {0.f, 0.f, 0.f, 0.f};
        if (sm < N) {
            bv0 = *reinterpret_cast<const float4*>(W + (size_t)sm * 512 + kc * 128 + k0 + sk);
            bv1 = *reinterpret_cast<const float4*>(W + (size_t)sm * 512 + kc * 128 + k0 + sk + 32);
        }
        *reinterpret_cast<float4*>(&Bs[sm][sk]) = bv0;
        *reinterpret_cast<float4*>(&Bs[sm][sk + 32]) = bv1;
        __syncthreads();

        #pragma unroll
        for (int h = 0; h < 2; h++) {
            frag8 a0 = *reinterpret_cast<const frag8*>(&As[wm + lrow][h * 32 + quad * 8]);
            frag8 a1 = *reinterpret_cast<const frag8*>(&As[wm + 16 + lrow][h * 32 + quad * 8]);
            frag8 b0 = *reinterpret_cast<const frag8*>(&Bs[wn + lrow][h * 32 + quad * 8]);
            frag8 b1 = *reinterpret_cast<const frag8*>(&Bs[wn + 16 + lrow][h * 32 + quad * 8]);

            acc[0][0] = __builtin_amdgcn_mfma_f32_16x16x32_bf16(a0, b0, acc[0][0], 0, 0, 0);
            acc[0][1] = __builtin_amdgcn_mfma_f32_16x16x32_bf16(a0, b1, acc[0][1], 0, 0, 0);
            acc[1][0] = __builtin_amdgcn_mfma_f32_16x16x32_bf16(a1, b0, acc[1][0], 0, 0, 0);
            acc[1][1] = __builtin_amdgcn_mfma_f32_16x16x32_bf16(a1, b1, acc[1][1], 0, 0, 0);
        }
        __syncthreads();
    }

    #pragma unroll
    for (int mi = 0; mi < 2; mi++) {
        #pragma unroll
        for (int nj = 0; nj < 2; nj++) {
            int col = wn + nj * 16 + lrow;
            if (col >= N) continue;
            #pragma unroll
            for (int r = 0; r < 4; r++) {
                int trow = tb + wm + mi * 16 + quad * 4 + r;     // t within batch
                float v = acc[mi][nj][r];
                if (col < 16)
                    atomicAdd(&xdt[((size_t)(bb * 1024 + trow)) * 16 + col], v);
                else if (col < 32)
                    atomicAdd(&BT[((size_t)(bb * 16 + col - 16)) * 1024 + trow], v);
                else
                    atomicAdd(&CT[((size_t)(bb * 16 + col - 32)) * 1024 + trow], v);
            }
        }
    }
}

// ---------------- full-row GEMM (N=256), 512 threads / 8 waves ------------------
// BK=64 staging (round-5 form; register pipeline regressed)
__global__ __launch_bounds__(512)
void rowgemm(const unsigned short* __restrict__ A,
             const float* __restrict__ Af,
             const unsigned short* __restrict__ W,
             const float* __restrict__ bias,
             const float* res,
             const float* g1, const float* b1, int gelu1,
             const float* g2, const float* b2,
             float* outF, unsigned short* outB, float* l2out,
             const unsigned short* clsW, const float* clsB, float* clsOut,
             int K)
{
    __shared__ __align__(16) unsigned short As[16][72];
    __shared__ __align__(16) unsigned short Bs[256][72];
    __shared__ float red[8][16][2];
    __shared__ float sq[16];
    __shared__ __align__(16) unsigned short hb[16][264];

    const int tid = threadIdx.x;
    const int w = tid >> 6, lane = tid & 63;
    const int lrow = lane & 15, quad = lane >> 4;
    const int m0 = blockIdx.x * 16;

    f32x4 acc[2] = {};

    for (int k0 = 0; k0 < K; k0 += 64) {
        if (tid < 64) {
            int r_ = tid >> 2, c8 = (tid & 3) * 8;
            if (Af) {
                const float* src = Af + (size_t)(m0 + r_) * K + k0;
                float4 v0 = *reinterpret_cast<const float4*>(src + c8);
                float4 v1 = *reinterpret_cast<const float4*>(src + c8 + 4);
                float4 v2 = *reinterpret_cast<const float4*>(src + c8 + 32);
                float4 v3 = *reinterpret_cast<const float4*>(src + c8 + 36);
                unsigned short* dst = &As[r_][c8];
                dst[0] = bf16bits(v0.x); dst[1] = bf16bits(v0.y);
                dst[2] = bf16bits(v0.z); dst[3] = bf16bits(v0.w);
                dst[4] = bf16bits(v1.x); dst[5] = bf16bits(v1.y);
                dst[6] = bf16bits(v1.z); dst[7] = bf16bits(v1.w);
                unsigned short* dst2 = &As[r_][c8 + 32];
                dst2[0] = bf16bits(v2.x); dst2[1] = bf16bits(v2.y);
                dst2[2] = bf16bits(v2.z); dst2[3] = bf16bits(v2.w);
                dst2[4] = bf16bits(v3.x); dst2[5] = bf16bits(v3.y);
                dst2[6] = bf16bits(v3.z); dst2[7] = bf16bits(v3.w);
            } else {
                float4 av0 = *reinterpret_cast<const float4*>(A + (size_t)(m0 + r_) * K + k0 + c8);
                float4 av1 = *reinterpret_cast<const float4*>(A + (size_t)(m0 + r_) * K + k0 + c8 + 32);
                *reinterpret_cast<float4*>(&As[r_][c8]) = av0;
                *reinterpret_cast<float4*>(&As[r_][c8 + 32]) = av1;
            }
        }
        #pragma unroll
        for (int i = 0; i < 2; i++) {
            int n = (tid >> 2) + i * 128;
            int c8 = (tid & 3) * 8;
            float4 bv0 = *reinterpret_cast<const float4*>(W + (size_t)n * K + k0 + c8);
            float4 bv1 = *reinterpret_cast<const float4*>(W + (size_t)n * K + k0 + c8 + 32);
            *reinterpret_cast<float4*>(&Bs[n][c8]) = bv0;
            *reinterpret_cast<float4*>(&Bs[n][c8 + 32]) = bv1;
        }
        __syncthreads();
        #pragma unroll
        for (int h = 0; h < 2; h++) {
            frag8 a = *reinterpret_cast<const frag8*>(&As[lrow][h * 32 + quad * 8]);
            #pragma unroll
            for (int nj = 0; nj < 2; nj++) {
                frag8 b = *reinterpret_cast<const frag8*>(&Bs[w * 32 + nj * 16 + lrow][h * 32 + quad * 8]);
                acc[nj] = __builtin_amdgcn_mfma_f32_16x16x32_bf16(a, b, acc[nj], 0, 0, 0);
            }
        }
        __syncthreads();
    }

    float v[2][4];
    #pragma unroll
    for (int nj = 0; nj < 2; nj++) {
        int col = w * 32 + nj * 16 + lrow;
        #pragma unroll
        for (int r = 0; r < 4; r++) {
            int row = m0 + quad * 4 + r;
            float t = acc[nj][r];
            if (bias) t += bias[col];
            if (res) t += res[(size_t)row * 256 + col];
            v[nj][r] = t;
        }
    }

    if (g1) {
        #pragma unroll
        for (int r = 0; r < 4; r++) {
            float s1 = v[0][r] + v[1][r];
            float s2 = v[0][r]*v[0][r] + v[1][r]*v[1][r];
            s1 = row_sum16(s1); s2 = row_sum16(s2);
            if (lrow == 0) { red[w][quad * 4 + r][0] = s1; red[w][quad * 4 + r][1] = s2; }
        }
        __syncthreads();
        #pragma unroll
        for (int r = 0; r < 4; r++) {
            int rr = quad * 4 + r;
            float t1 = 0.f, t2 = 0.f;
            #pragma unroll
            for (int ww = 0; ww < 8; ww++) { t1 += red[ww][rr][0]; t2 += red[ww][rr][1]; }
            float mu = t1 * (1.0f / 256.0f);
            float var = t2 * (1.0f / 256.0f) - mu * mu;
            float rstd = rsqrtf(var + 1e-5f);
            #pragma unroll
            for (int nj = 0; nj < 2; nj++) {
                int col = w * 32 + nj * 16 + lrow;
                float t = (v[nj][r] - mu) * rstd * g1[col] + b1[col];
                if (gelu1) t = gelu_exact(t);
                v[nj][r] = t;
            }
        }
        __syncthreads();
    } else if (gelu1) {
        #pragma unroll
        for (int nj = 0; nj < 2; nj++)
            #pragma unroll
            for (int r = 0; r < 4; r++)
                v[nj][r] = gelu_exact(v[nj][r]);
    }

    if (outF) {
        #pragma unroll
        for (int nj = 0; nj < 2; nj++) {
            int col = w * 32 + nj * 16 + lrow;
            #pragma unroll
            for (int r = 0; r < 4; r++)
                outF[(size_t)(m0 + quad * 4 + r) * 256 + col] = v[nj][r];
        }
    }

    if (l2out) {
        #pragma unroll
        for (int r = 0; r < 4; r++) {
            float s2 = v[0][r]*v[0][r] + v[1][r]*v[1][r];
            s2 = row_sum16(s2);
            if (lrow == 0) red[w][quad * 4 + r][0] = s2;
        }
        __syncthreads();
        if (tid < 16) {
            float t = 0.f;
            #pragma unroll
            for (int ww = 0; ww < 8; ww++) t += red[ww][tid][0];
            sq[tid] = sqrtf(t);
        }
        __syncthreads();
        if (tid == 0) {
            float a = 0.f;
            #pragma unroll
            for (int i = 0; i < 16; i++) a += sq[i];
            atomicAdd(l2out, a * (0.01f / 4096.0f));
        }
    }

    if (g2) {
        __syncthreads();
        #pragma unroll
        for (int r = 0; r < 4; r++) {
            float s1 = v[0][r] + v[1][r];
            float s2 = v[0][r]*v[0][r] + v[1][r]*v[1][r];
            s1 = row_sum16(s1); s2 = row_sum16(s2);
            if (lrow == 0) { red[w][quad * 4 + r][0] = s1; red[w][quad * 4 + r][1] = s2; }
        }
        __syncthreads();
        #pragma unroll
        for (int r = 0; r < 4; r++) {
            int rr = quad * 4 + r;
            float t1 = 0.f, t2 = 0.f;
            #pragma unroll
            for (int ww = 0; ww < 8; ww++) { t1 += red[ww][rr][0]; t2 += red[ww][rr][1]; }
            float mu = t1 * (1.0f / 256.0f);
            float var = t2 * (1.0f / 256.0f) - mu * mu;
            float rstd = rsqrtf(var + 1e-5f);
            #pragma unroll
            for (int nj = 0; nj < 2; nj++) {
                int col = w * 32 + nj * 16 + lrow;
                outB[(size_t)(m0 + rr) * 256 + col] = bf16bits((v[nj][r] - mu) * rstd * g2[col] + b2[col]);
            }
        }
    } else if (outB) {
        #pragma unroll
        for (int nj = 0; nj < 2; nj++) {
            int col = w * 32 + nj * 16 + lrow;
            #pragma unroll
            for (int r = 0; r < 4; r++)
                outB[(size_t)(m0 + quad * 4 + r) * 256 + col] = bf16bits(v[nj][r]);
        }
    }

    // ---- fused cls GEMM: logits(16 x 128) = v(16 x 256) @ clsW(128 x 256)^T ----
    if (clsW) {
        #pragma unroll
        for (int nj = 0; nj < 2; nj++) {
            int col = w * 32 + nj * 16 + lrow;
            #pragma unroll
            for (int r = 0; r < 4; r++)
                hb[quad * 4 + r][col] = bf16bits(v[nj][r]);
        }
        __syncthreads();
        f32x4 cacc = {};
        #pragma unroll
        for (int k0 = 0; k0 < 256; k0 += 32) {
            frag8 a = *reinterpret_cast<const frag8*>(&hb[lrow][k0 + quad * 8]);
            frag8 b = *reinterpret_cast<const frag8*>(clsW + (size_t)(w * 16 + lrow) * 256 + k0 + quad * 8);
            cacc = __builtin_amdgcn_mfma_f32_16x16x32_bf16(a, b, cacc, 0, 0, 0);
        }
        int col = w * 16 + lrow;
        float cb = clsB[col];
        #pragma unroll
        for (int r = 0; r < 4; r++)
            clsOut[(size_t)(m0 + quad * 4 + r) * 128 + col] = cacc[r] + cb;
    }
}

// ---------------- chunked selective scan (round-5 serial structure) -------------
// B/C 1-deep prefetch (2-deep bought ~1 µs only); dt/ut LDS reads prefetched one
// q ahead into registers (VGPR-neutral swap; targets correlated ds_read stalls).
__global__ __launch_bounds__(1024)
void scan_chunked(const float* __restrict__ xdt,
                  const float* __restrict__ dtw, const float* __restrict__ dtb,
                  const float* __restrict__ ucT,
                  const float* __restrict__ BT, const float* __restrict__ CT,
                  const unsigned short* __restrict__ szT,
                  const float* __restrict__ Ac,
                  const float* __restrict__ Dp,
                  unsigned short* __restrict__ y)
{
    __shared__ float aprod_s[16][64];
    __shared__ float sfin_s[16][64];
    __shared__ float sin_w[16][64];
    __shared__ __align__(16) float ylocal[16][64][4];
    __shared__ __align__(16) float dltS[4][1032];
    __shared__ __align__(16) float ucS[4][1032];

    const int j = blockIdx.x;
    const int bid = (j & 7) * 64 + (j >> 3);     // XCD swizzle
    const int b = bid >> 7;
    const int d0 = (bid & 127) * 4;
    const int w = threadIdx.x >> 6;
    const int lane = threadIdx.x & 63;
    const int dsub = lane >> 4, s = lane & 15;
    const int d = d0 + dsub;
    const int t = w * 64 + lane;

    const float Acoef = Ac[d * 16 + s];          // already * log2(e)

    const float4* Bp = reinterpret_cast<const float4*>(BT + ((size_t)(b * 16 + s)) * 1024 + w * 64);
    const float4* Cp = reinterpret_cast<const float4*>(CT + ((size_t)(b * 16 + s)) * 1024 + w * 64);

    // ---- issue long-latency loads first: uc stage, xdt, B/C tile 0, sz ----
    {
        int dd = lane >> 4, tq = (lane & 15) * 4;
        float4 v = *reinterpret_cast<const float4*>(ucT + ((size_t)(b * 512 + d0 + dd)) * 1024 + w * 64 + tq);
        *reinterpret_cast<float4*>(&ucS[dd][w * 64 + tq]) = v;
    }
    const float* xr = xdt + ((size_t)(b * 1024) + t) * 16;
    float4 x0 = *reinterpret_cast<const float4*>(xr + 0);
    float4 x1 = *reinterpret_cast<const float4*>(xr + 4);
    float4 x2 = *reinterpret_cast<const float4*>(xr + 8);
    float4 x3 = *reinterpret_cast<const float4*>(xr + 12);
    float4 B4 = Bp[0], C4 = Cp[0];
    unsigned short szr[4];
    #pragma unroll
    for (int dd = 0; dd < 4; dd++)
        szr[dd] = szT[((size_t)(b * 512 + d0 + dd)) * 1024 + t];

    // ---- front-end: compute dlt for own chunk (lane = t) ----
    #pragma unroll
    for (int dd = 0; dd < 4; dd++) {
        const float* wt = dtw + (size_t)(d0 + dd) * 16;
        float a2 = dtb[d0 + dd]
            + x0.x * wt[0]  + x0.y * wt[1]  + x0.z * wt[2]  + x0.w * wt[3]
            + x1.x * wt[4]  + x1.y * wt[5]  + x1.z * wt[6]  + x1.w * wt[7]
            + x2.x * wt[8]  + x2.y * wt[9]  + x2.z * wt[10] + x2.w * wt[11]
            + x3.x * wt[12] + x3.y * wt[13] + x3.z * wt[14] + x3.w * wt[15];
        dltS[dd][t] = softplus_f(a2);
    }

    // ---- Phase A: local scan (B/C + dt/ut 1-deep prefetch; per-jj y stores) ----
    float st = 0.0f, ap = 1.0f;
    float4 dt4 = *reinterpret_cast<const float4*>(&dltS[dsub][w * 64]);
    float4 ut4 = *reinterpret_cast<const float4*>(&ucS[dsub][w * 64]);
    #pragma unroll
    for (int q = 0; q < 16; q++) {
        float4 nB, nC, ndt, nut;
        if (q < 15) {
            nB = Bp[q + 1]; nC = Cp[q + 1];
            ndt = *reinterpret_cast<const float4*>(&dltS[dsub][w * 64 + (q + 1) * 4]);
            nut = *reinterpret_cast<const float4*>(&ucS[dsub][w * 64 + (q + 1) * 4]);
        }
        const float* dtp = (const float*)&dt4;
        const float* utp = (const float*)&ut4;
        const float* Btp = (const float*)&B4;
        const float* Ctp = (const float*)&C4;
        #pragma unroll
        for (int jj = 0; jj < 4; jj++) {
            float dA = exp2_raw(dtp[jj] * Acoef);
            st = st * dA + dtp[jj] * utp[jj] * Btp[jj];
            ap *= dA;
            float part = row_sum16(st * Ctp[jj]);
            if (s == 0) ylocal[w][q * 4 + jj][dsub] = part;
        }
        B4 = nB; C4 = nC; dt4 = ndt; ut4 = nut;
    }
    aprod_s[w][lane] = ap;
    sfin_s[w][lane] = st;
    __syncthreads();                                 // the only barrier

    // ---- decentralized combine ----
    {
        float pre = 0.0f;
        #pragma unroll
        for (int c = 0; c < 15; c++) {
            float apc = aprod_s[c][lane];
            float sfc = sfin_s[c][lane];
            float cand = sfc + apc * pre;
            pre = (c < w) ? cand : pre;
        }
        sin_w[w][lane] = pre;
    }

    // ---- Phase C: lane = t; correction via prefix sums + epilogue ----
    float cums[4];
    #pragma unroll
    for (int dd = 0; dd < 4; dd++)
        cums[dd] = dltS[dd][t];
    #pragma unroll
    for (int dd = 0; dd < 4; dd++)
        cums[dd] = prefix_sum64(cums[dd]);

    float4 yl = *reinterpret_cast<const float4*>(&ylocal[w][lane][0]);
    float acc[4] = { yl.x, yl.y, yl.z, yl.w };

    float Cs[4];
    #pragma unroll
    for (int jj = 0; jj < 4; jj++)
        Cs[jj] = CT[((size_t)(b * 16 + jj)) * 1024 + t];
    #pragma unroll
    for (int sq = 0; sq < 4; sq++) {
        float Csn[4];
        if (sq < 3) {
            #pragma unroll
            for (int jj = 0; jj < 4; jj++)
                Csn[jj] = CT[((size_t)(b * 16 + (sq + 1) * 4 + jj)) * 1024 + t];
        }
        #pragma unroll
        for (int dd = 0; dd < 4; dd++) {
            float4 sin4 = *reinterpret_cast<const float4*>(&sin_w[w][dd * 16 + sq * 4]);
            const float* sp = (const float*)&sin4;
            #pragma unroll
            for (int jj = 0; jj < 4; jj++) {
                float ac = Ac[(d0 + dd) * 16 + sq * 4 + jj];      // already * log2(e)
                acc[dd] += sp[jj] * Cs[jj] * exp2_raw(ac * cums[dd]);
            }
        }
        #pragma unroll
        for (int jj = 0; jj < 4; jj++) Cs[jj] = Csn[jj];
    }

    const size_t row = (size_t)b * 1024 + t;
    ushort4 yo;
    {
        float ut0 = ucS[0][t], ut1 = ucS[1][t], ut2 = ucS[2][t], ut3 = ucS[3][t];
        float y0 = (acc[0] + ut0 * Dp[d0 + 0]) * bf2f(szr[0]);
        float y1 = (acc[1] + ut1 * Dp[d0 + 1]) * bf2f(szr[1]);
        float y2 = (acc[2] + ut2 * Dp[d0 + 2]) * bf2f(szr[2]);
        float y3 = (acc[3] + ut3 * Dp[d0 + 3]) * bf2f(szr[3]);
        yo.x = bf16bits(y0); yo.y = bf16bits(y1);
        yo.z = bf16bits(y2); yo.w = bf16bits(y3);
    }
    *reinterpret_cast<ushort4*>(y + row * 512 + d0) = yo;
}

// ---------------- launcher ----------------
extern "C" void kernel_launch(void* const* d_in, const int* in_sizes, int n_in,
                              void* d_out, int out_size, void* d_ws, size_t ws_size,
                              hipStream_t stream)
{
    const float* x      = (const float*)d_in[0];
    const float* in_b   = (const float*)d_in[2];
    const float* ln_g   = (const float*)d_in[3];
    const float* ln_b   = (const float*)d_in[4];
    const float* blk_ng  = (const float*)d_in[5];
    const float* blk_nb  = (const float*)d_in[6];
    const float* blk_cw  = (const float*)d_in[8];
    const float* blk_cb  = (const float*)d_in[9];
    const float* blk_dtw = (const float*)d_in[11];
    const float* blk_dtb = (const float*)d_in[12];
    const float* blk_Alog= (const float*)d_in[13];
    const float* blk_D   = (const float*)d_in[14];
    const float* op_b   = (const float*)d_in[17];
    const float* cls_b  = (const float*)d_in[19];
    float* out = (float*)d_out;

    const int BL = 4096;
    float* ws = (float*)d_ws;
    float* h0   = ws;                         // 1,048,576
    float* xzuT = h0 + 1048576;               // 2,097,152  [b][d][t] fp32 (u pre-conv)
    float* ucT  = xzuT + 2097152;             // 2,097,152  [b][d][t]
    float* xdt  = ucT + 2097152;              // 131,072 (2 layers x 4096x16)
    float* BT   = xdt + 131072;               // 131,072 (2 layers x [b][s][t])
    float* CT   = BT + 131072;                // 131,072
    float* Ac   = CT + 131072;                // 16,384
    unsigned short* szT = (unsigned short*)(Ac + 16384);  // 2,097,152 bf16 [b][d][t]
    unsigned short* wb  = szT + 2097152;      // 1,130,496
    unsigned short* hnb = wb + 1130496;       // 1,048,576
    unsigned short* ybb = hnb + 1048576;      // 2,097,152
    unsigned short* h0b = hnb;
    unsigned short* in_wb  = wb;
    unsigned short* ipw_b  = wb + 196608;
    unsigned short* xpw_b  = wb + 720896;
    unsigned short* opw_b  = wb + 770048;
    unsigned short* op_wb  = wb + 1032192;
    unsigned short* cls_wb = wb + 1097728;

    CvtArgs ca;
    ca.src[0] = (const float*)d_in[1];  ca.dst[0] = in_wb;  ca.n4[0] = 196608 / 4;
    ca.src[1] = (const float*)d_in[7];  ca.dst[1] = ipw_b;  ca.n4[1] = 524288 / 4;
    ca.src[2] = (const float*)d_in[10]; ca.dst[2] = xpw_b;  ca.n4[2] = 49152 / 4;
    ca.src[3] = (const float*)d_in[15]; ca.dst[3] = opw_b;  ca.n4[3] = 262144 / 4;
    ca.src[4] = (const float*)d_in[16]; ca.dst[4] = op_wb;  ca.n4[4] = 65536 / 4;
    ca.src[5] = (const float*)d_in[18]; ca.dst[5] = cls_wb; ca.n4[5] = 32768 / 4;
    int total4 = 1130496 / 4;
    int zquads = 393216 / 4;                  // xdt+BT+CT (both layers, contiguous)
    int totalg = total4 + 16384 + zquads;
    cvt_all<<<(totalg + 255) / 256, 256, 0, stream>>>(ca, total4, blk_Alog, Ac,
                                                      xdt, zquads,
                                                      out + (size_t)BL * 128);

    // in_proj (A from fp32 x) + bias + LN + GELU -> h0 (fp32), + LN(layer0) -> hnb
    rowgemm<<<256, 512, 0, stream>>>(nullptr, x, in_wb, in_b, nullptr,
                                     ln_g, ln_b, 1,
                                     blk_ng, blk_nb,
                                     h0, hnb, nullptr,
                                     nullptr, nullptr, nullptr, 768);

    for (int l = 0; l < 2; l++) {
        const float* cw   = blk_cw  + (size_t)l * 512 * 4;
        const float* cb   = blk_cb  + l * 512;
        const float* dtw  = blk_dtw + (size_t)l * 512 * 16;
        const float* dtb  = blk_dtb + l * 512;
        const float* Dl   = blk_D   + l * 512;
        const unsigned short* ipwl = ipw_b + (size_t)l * 262144;
        const unsigned short* xpwl = xpw_b + (size_t)l * 24576;
        const unsigned short* opwl = opw_b + (size_t)l * 131072;
        float* xdtl = xdt + (size_t)l * 65536;
        float* BTl  = BT  + (size_t)l * 65536;
        float* CTl  = CT  + (size_t)l * 65536;

        // ipw GEMM: u -> xzuT fp32 [b][d][t]; z -> silu(z) bf16 szT [b][d][t]
        gemm_ipw<<<dim3(16, 64), 256, 0, stream>>>(hnb, ipwl, xzuT, szT);
        // fused conv + xpw projection (K-split x4): ucT + atomic xdt/BT/CT
        gemm_cat<<<dim3(4, 64), 256, 0, stream>>>(xzuT, xpwl, cw, cb, ucT, xdtl, BTl, CTl);
        // scan (computes dlt from xdt in-kernel) -> ybb
        scan_chunked<<<512, 1024, 0, stream>>>(xdtl, dtw, dtb, ucT, BTl, CTl, szT,
                                               Ac + (size_t)l * 8192, Dl, ybb);
        // h0 += ybb @ opw.T; layer0: +LN(layer1)->hnb; layer1: ->h0b bf16 only
        if (l == 0)
            rowgemm<<<256, 512, 0, stream>>>(ybb, nullptr, opwl, nullptr, h0,
                                             nullptr, nullptr, 0,
                                             blk_ng + 256, blk_nb + 256,
                                             h0, hnb, nullptr,
                                             nullptr, nullptr, nullptr, 512);
        else
            rowgemm<<<256, 512, 0, stream>>>(ybb, nullptr, opwl, nullptr, h0,
                                             nullptr, nullptr, 0,
                                             nullptr, nullptr,
                                             nullptr, h0b, nullptr,
                                             nullptr, nullptr, nullptr, 512);
    }

    // final: h2 = gelu(h0b @ op_w.T + op_b); fused L2 scalar + cls GEMM -> out
    rowgemm<<<256, 512, 0, stream>>>(h0b, nullptr, op_wb, op_b, nullptr,
                                     nullptr, nullptr, 1,
                                     nullptr, nullptr,
                                     nullptr, nullptr, out + (size_t)BL * 128,
                                     cls_wb, cls_b, out, 256);
}

// Round 9
// 281.571 us; speedup vs baseline: 1.1175x; 1.0167x over previous
//
#include <hip/hip_runtime.h>
#include <hip/hip_bf16.h>
#include <math.h>

typedef __attribute__((ext_vector_type(8))) short frag8;   // 8 bf16 (4 VGPRs)
typedef __attribute__((ext_vector_type(4))) float f32x4;

// ---------------- device helpers ----------------
__device__ __forceinline__ float gelu_exact(float x) {
    return 0.5f * x * (1.0f + erff(x * 0.70710678118654752f));
}
// raw v_exp_f32 (2^x, flush-to-zero)
__device__ __forceinline__ float exp2_raw(float x) {
    return __builtin_amdgcn_exp2f(x);
}
// softplus via native exp2/log2: log(1+e^x) = log2(1+2^(x*log2e)) * ln2
__device__ __forceinline__ float softplus_f(float x) {
    float e = exp2_raw(x * 1.4426950408889634f);
    float sp = __log2f(1.0f + e) * 0.6931471805599453f;
    return (x > 20.0f) ? x : sp;
}
__device__ __forceinline__ float sigmoid_f(float x) {
    return 1.0f / (1.0f + __expf(-x));
}
__device__ __forceinline__ unsigned short bf16bits(float x) {
    __hip_bfloat16 h = __float2bfloat16(x);
    return *(unsigned short*)&h;
}
__device__ __forceinline__ float bf2f(unsigned short u) {
    unsigned int v = ((unsigned int)u) << 16;
    return __builtin_bit_cast(float, v);
}
// sum over the 16 lanes of each DPP row-of-16 — VALU-pipe only
__device__ __forceinline__ float row_sum16(float x) {
    int t;
    t = __builtin_amdgcn_update_dpp(0, __builtin_bit_cast(int, x), 0x128, 0xf, 0xf, true); // row_ror:8
    x += __builtin_bit_cast(float, t);
    t = __builtin_amdgcn_update_dpp(0, __builtin_bit_cast(int, x), 0x124, 0xf, 0xf, true); // row_ror:4
    x += __builtin_bit_cast(float, t);
    t = __builtin_amdgcn_update_dpp(0, __builtin_bit_cast(int, x), 0x122, 0xf, 0xf, true); // row_ror:2
    x += __builtin_bit_cast(float, t);
    t = __builtin_amdgcn_update_dpp(0, __builtin_bit_cast(int, x), 0x121, 0xf, 0xf, true); // row_ror:1
    x += __builtin_bit_cast(float, t);
    return x;
}
// inclusive prefix sum over the full 64-lane wave (DPP, VALU-pipe only)
__device__ __forceinline__ float prefix_sum64(float x) {
    int t;
    t = __builtin_amdgcn_update_dpp(0, __builtin_bit_cast(int, x), 0x111, 0xf, 0xf, true); // row_shr:1
    x += __builtin_bit_cast(float, t);
    t = __builtin_amdgcn_update_dpp(0, __builtin_bit_cast(int, x), 0x112, 0xf, 0xf, true); // row_shr:2
    x += __builtin_bit_cast(float, t);
    t = __builtin_amdgcn_update_dpp(0, __builtin_bit_cast(int, x), 0x114, 0xf, 0xf, true); // row_shr:4
    x += __builtin_bit_cast(float, t);
    t = __builtin_amdgcn_update_dpp(0, __builtin_bit_cast(int, x), 0x118, 0xf, 0xf, true); // row_shr:8
    x += __builtin_bit_cast(float, t);
    t = __builtin_amdgcn_update_dpp(0, __builtin_bit_cast(int, x), 0x142, 0xa, 0xf, true); // row_bcast:15
    x += __builtin_bit_cast(float, t);
    t = __builtin_amdgcn_update_dpp(0, __builtin_bit_cast(int, x), 0x143, 0xc, 0xf, true); // row_bcast:31
    x += __builtin_bit_cast(float, t);
    return x;
}

// -------- fp32->bf16 weight cvt + Acoef + l2 zero + zero xdt/BT/CT (both layers)
struct CvtArgs {
    const float* src[6];
    unsigned short* dst[6];
    int n4[6];
};
__global__ __launch_bounds__(256)
void cvt_all(CvtArgs a, int total4, const float* __restrict__ Alog,
             float* __restrict__ Ac, float* __restrict__ Z, int zquads, float* l2)
{
    int i = blockIdx.x * 256 + threadIdx.x;
    if (i >= total4) {
        int j = i - total4;
        if (j < 16384) {
            Ac[j] = -__expf(Alog[j]) * 1.4426950408889634f;
        } else {
            int z = j - 16384;
            if (z < zquads) {
                float4 zero = {0.f, 0.f, 0.f, 0.f};
                reinterpret_cast<float4*>(Z)[z] = zero;
            }
        }
        if (j == 0) *l2 = 0.0f;
        return;
    }
    int seg = 0;
    while (i >= a.n4[seg]) { i -= a.n4[seg]; seg++; }
    float4 v = reinterpret_cast<const float4*>(a.src[seg])[i];
    ushort4 o;
    o.x = bf16bits(v.x); o.y = bf16bits(v.y); o.z = bf16bits(v.z); o.w = bf16bits(v.w);
    reinterpret_cast<ushort4*>(a.dst[seg])[i] = o;
}

// ---------------- ipw GEMM (N=1024, K=256): u-half -> xzuT fp32 [b][d][t],
// ---------------- z-half -> silu(z) bf16 szT [b][d][t] ----------------
// BK=128: 2 stage+barrier iterations for K=256 (was 4 at BK=64)
__global__ __launch_bounds__(256)
void gemm_ipw(const unsigned short* __restrict__ A,
              const unsigned short* __restrict__ W,
              float* __restrict__ xzuT,
              unsigned short* __restrict__ szT)
{
    __shared__ __align__(16) unsigned short As[64][136];
    __shared__ __align__(16) unsigned short Bs[64][136];

    const int tid = threadIdx.x;
    const int wid = tid >> 6, lane = tid & 63;
    const int wm = (wid >> 1) * 32, wn = (wid & 1) * 32;
    const int m0 = blockIdx.y * 64, n0 = blockIdx.x * 64;
    const int lrow = lane & 15, quad = lane >> 4;
    const int K = 256;

    const int sm = tid >> 2;
    const int sk = (tid & 3) * 32;

    f32x4 acc[2][2] = {};

    for (int k0 = 0; k0 < K; k0 += 128) {
        #pragma unroll
        for (int q = 0; q < 4; q++) {
            *reinterpret_cast<float4*>(&As[sm][sk + q * 8]) =
                *reinterpret_cast<const float4*>(A + (size_t)(m0 + sm) * K + k0 + sk + q * 8);
            *reinterpret_cast<float4*>(&Bs[sm][sk + q * 8]) =
                *reinterpret_cast<const float4*>(W + (size_t)(n0 + sm) * K + k0 + sk + q * 8);
        }
        __syncthreads();

        #pragma unroll
        for (int h = 0; h < 4; h++) {
            frag8 a0 = *reinterpret_cast<const frag8*>(&As[wm + lrow][h * 32 + quad * 8]);
            frag8 a1 = *reinterpret_cast<const frag8*>(&As[wm + 16 + lrow][h * 32 + quad * 8]);
            frag8 b0 = *reinterpret_cast<const frag8*>(&Bs[wn + lrow][h * 32 + quad * 8]);
            frag8 b1 = *reinterpret_cast<const frag8*>(&Bs[wn + 16 + lrow][h * 32 + quad * 8]);

            acc[0][0] = __builtin_amdgcn_mfma_f32_16x16x32_bf16(a0, b0, acc[0][0], 0, 0, 0);
            acc[0][1] = __builtin_amdgcn_mfma_f32_16x16x32_bf16(a0, b1, acc[0][1], 0, 0, 0);
            acc[1][0] = __builtin_amdgcn_mfma_f32_16x16x32_bf16(a1, b0, acc[1][0], 0, 0, 0);
            acc[1][1] = __builtin_amdgcn_mfma_f32_16x16x32_bf16(a1, b1, acc[1][1], 0, 0, 0);
        }
        __syncthreads();
    }

    const int bb = m0 >> 10;
    const int tb = m0 & 1023;
    #pragma unroll
    for (int mi = 0; mi < 2; mi++) {
        int t4 = tb + wm + mi * 16 + quad * 4;
        #pragma unroll
        for (int nj = 0; nj < 2; nj++) {
            int col = n0 + wn + nj * 16 + lrow;
            if (col < 512) {
                float4 o = { acc[mi][nj][0], acc[mi][nj][1], acc[mi][nj][2], acc[mi][nj][3] };
                *reinterpret_cast<float4*>(xzuT + ((size_t)(bb * 512 + col)) * 1024 + t4) = o;
            } else {
                int z = col - 512;
                ushort4 o;
                float v0 = acc[mi][nj][0], v1 = acc[mi][nj][1], v2 = acc[mi][nj][2], v3 = acc[mi][nj][3];
                o.x = bf16bits(v0 * sigmoid_f(v0));
                o.y = bf16bits(v1 * sigmoid_f(v1));
                o.z = bf16bits(v2 * sigmoid_f(v2));
                o.w = bf16bits(v3 * sigmoid_f(v3));
                *reinterpret_cast<ushort4*>(szT + ((size_t)(bb * 512 + z)) * 1024 + t4) = o;
            }
        }
    }
}

// ---------------- conv4+SiLU fused into xpw projection, K-split x4 --------------
// BK=128: SINGLE stage + one barrier (its K-slice is exactly 128)
__global__ __launch_bounds__(256)
void gemm_cat(const float* __restrict__ xzuT,
              const unsigned short* __restrict__ W,     // xpw: 48 x 512 bf16
              const float* __restrict__ cw, const float* __restrict__ cb,
              float* __restrict__ ucT,
              float* __restrict__ xdt, float* __restrict__ BT, float* __restrict__ CT)
{
    __shared__ __align__(16) unsigned short As[64][136];
    __shared__ __align__(16) unsigned short Bs[64][136];

    const int tid = threadIdx.x;
    const int wid = tid >> 6, lane = tid & 63;
    const int wm = (wid >> 1) * 32, wn = (wid & 1) * 32;
    const int kc = blockIdx.x;            // 0..3 (128-d chunk)
    const int m0 = blockIdx.y * 64;
    const int bb = m0 >> 10;
    const int tb = m0 & 1023;
    const int lrow = lane & 15, quad = lane >> 4;
    const int N = 48;

    const int sm = tid >> 2;
    const int sk = (tid & 3) * 32;

    f32x4 acc[2][2] = {};

    {
        #pragma unroll
        for (int p = 0; p < 8; p++) {
            int kk = (tid >> 4) + p * 16;
            int k  = kc * 128 + kk;
            int mq = tid & 15;
            int tg = tb + mq * 4;
            const float* rowp = xzuT + ((size_t)(bb * 512 + k)) * 1024;
            float4 cur = *reinterpret_cast<const float4*>(rowp + tg);
            float4 prev = {0.f, 0.f, 0.f, 0.f};
            if (tg != 0) prev = *reinterpret_cast<const float4*>(rowp + tg - 4);
            float4 cv = *reinterpret_cast<const float4*>(cw + k * 4);
            float cbv = cb[k];
            float o0 = cbv + cv.x*prev.y + cv.y*prev.z + cv.z*prev.w + cv.w*cur.x;
            float o1 = cbv + cv.x*prev.z + cv.y*prev.w + cv.z*cur.x  + cv.w*cur.y;
            float o2 = cbv + cv.x*prev.w + cv.y*cur.x  + cv.z*cur.y  + cv.w*cur.z;
            float o3 = cbv + cv.x*cur.x  + cv.y*cur.y  + cv.z*cur.z  + cv.w*cur.w;
            o0 *= sigmoid_f(o0); o1 *= sigmoid_f(o1);
            o2 *= sigmoid_f(o2); o3 *= sigmoid_f(o3);
            float4 uo = { o0, o1, o2, o3 };
            *reinterpret_cast<float4*>(ucT + ((size_t)(bb * 512 + k)) * 1024 + tg) = uo;
            As[mq * 4 + 0][kk] = bf16bits(o0);
            As[mq * 4 + 1][kk] = bf16bits(o1);
            As[mq * 4 + 2][kk] = bf16bits(o2);
            As[mq * 4 + 3][kk] = bf16bits(o3);
        }
        #pragma unroll
        for (int q = 0; q < 4; q++) {
            float4 bv = {0.f, 0.f, 0.f, 0.f};
            if (sm < N) bv = *reinterpret_cast<const float4*>(W + (size_t)sm * 512 + kc * 128 + sk + q * 8);
            *reinterpret_cast<float4*>(&Bs[sm][sk + q * 8]) = bv;
        }
        __syncthreads();

        #pragma unroll
        for (int h = 0; h < 4; h++) {
            frag8 a0 = *reinterpret_cast<const frag8*>(&As[wm + lrow][h * 32 + quad * 8]);
            frag8 a1 = *reinterpret_cast<const frag8*>(&As[wm + 16 + lrow][h * 32 + quad * 8]);
            frag8 b0 = *reinterpret_cast<const frag8*>(&Bs[wn + lrow][h * 32 + quad * 8]);
            frag8 b1 = *reinterpret_cast<const frag8*>(&Bs[wn + 16 + lrow][h * 32 + quad * 8]);

            acc[0][0] = __builtin_amdgcn_mfma_f32_16x16x32_bf16(a0, b0, acc[0][0], 0, 0, 0);
            acc[0][1] = __builtin_amdgcn_mfma_f32_16x16x32_bf16(a0, b1, acc[0][1], 0, 0, 0);
            acc[1][0] = __builtin_amdgcn_mfma_f32_16x16x32_bf16(a1, b0, acc[1][0], 0, 0, 0);
            acc[1][1] = __builtin_amdgcn_mfma_f32_16x16x32_bf16(a1, b1, acc[1][1], 0, 0, 0);
        }
    }

    #pragma unroll
    for (int mi = 0; mi < 2; mi++) {
        #pragma unroll
        for (int nj = 0; nj < 2; nj++) {
            int col = wn + nj * 16 + lrow;
            if (col >= N) continue;
            #pragma unroll
            for (int r = 0; r < 4; r++) {
                int trow = tb + wm + mi * 16 + quad * 4 + r;     // t within batch
                float v = acc[mi][nj][r];
                if (col < 16)
                    atomicAdd(&xdt[((size_t)(bb * 1024 + trow)) * 16 + col], v);
                else if (col < 32)
                    atomicAdd(&BT[((size_t)(bb * 16 + col - 16)) * 1024 + trow], v);
                else
                    atomicAdd(&CT[((size_t)(bb * 16 + col - 32)) * 1024 + trow], v);
            }
        }
    }
}

// ---------------- full-row GEMM (N=256), 512 threads / 8 waves ------------------
// BK=128 staging: K=768 -> 6 iterations (was 12), K=512 -> 4, K=256 -> 2
__global__ __launch_bounds__(512)
void rowgemm(const unsigned short* __restrict__ A,
             const float* __restrict__ Af,
             const unsigned short* __restrict__ W,
             const float* __restrict__ bias,
             const float* res,
             const float* g1, const float* b1, int gelu1,
             const float* g2, const float* b2,
             float* outF, unsigned short* outB, float* l2out,
             const unsigned short* clsW, const float* clsB, float* clsOut,
             int K)
{
    __shared__ __align__(16) unsigned short As[16][136];
    __shared__ __align__(16) unsigned short Bs[256][136];
    __shared__ float red[8][16][2];
    __shared__ float sq[16];
    __shared__ __align__(16) unsigned short hb[16][264];

    const int tid = threadIdx.x;
    const int w = tid >> 6, lane = tid & 63;
    const int lrow = lane & 15, quad = lane >> 4;
    const int m0 = blockIdx.x * 16;

    f32x4 acc[2] = {};

    for (int k0 = 0; k0 < K; k0 += 128) {
        if (tid < 64) {
            int r_ = tid >> 2, c32 = (tid & 3) * 32;
            if (Af) {
                const float* src = Af + (size_t)(m0 + r_) * K + k0 + c32;
                unsigned short* dst = &As[r_][c32];
                #pragma unroll
                for (int q = 0; q < 8; q++) {
                    float4 v = *reinterpret_cast<const float4*>(src + q * 4);
                    dst[q * 4 + 0] = bf16bits(v.x);
                    dst[q * 4 + 1] = bf16bits(v.y);
                    dst[q * 4 + 2] = bf16bits(v.z);
                    dst[q * 4 + 3] = bf16bits(v.w);
                }
            } else {
                #pragma unroll
                for (int q = 0; q < 4; q++)
                    *reinterpret_cast<float4*>(&As[r_][c32 + q * 8]) =
                        *reinterpret_cast<const float4*>(A + (size_t)(m0 + r_) * K + k0 + c32 + q * 8);
            }
        }
        {
            int c32 = (tid & 3) * 32;
            #pragma unroll
            for (int i = 0; i < 2; i++) {
                int n = (tid >> 2) + i * 128;
                #pragma unroll
                for (int q = 0; q < 4; q++)
                    *reinterpret_cast<float4*>(&Bs[n][c32 + q * 8]) =
                        *reinterpret_cast<const float4*>(W + (size_t)n * K + k0 + c32 + q * 8);
            }
        }
        __syncthreads();
        #pragma unroll
        for (int h = 0; h < 4; h++) {
            frag8 a = *reinterpret_cast<const frag8*>(&As[lrow][h * 32 + quad * 8]);
            #pragma unroll
            for (int nj = 0; nj < 2; nj++) {
                frag8 b = *reinterpret_cast<const frag8*>(&Bs[w * 32 + nj * 16 + lrow][h * 32 + quad * 8]);
                acc[nj] = __builtin_amdgcn_mfma_f32_16x16x32_bf16(a, b, acc[nj], 0, 0, 0);
            }
        }
        __syncthreads();
    }

    float v[2][4];
    #pragma unroll
    for (int nj = 0; nj < 2; nj++) {
        int col = w * 32 + nj * 16 + lrow;
        #pragma unroll
        for (int r = 0; r < 4; r++) {
            int row = m0 + quad * 4 + r;
            float t = acc[nj][r];
            if (bias) t += bias[col];
            if (res) t += res[(size_t)row * 256 + col];
            v[nj][r] = t;
        }
    }

    if (g1) {
        #pragma unroll
        for (int r = 0; r < 4; r++) {
            float s1 = v[0][r] + v[1][r];
            float s2 = v[0][r]*v[0][r] + v[1][r]*v[1][r];
            s1 = row_sum16(s1); s2 = row_sum16(s2);
            if (lrow == 0) { red[w][quad * 4 + r][0] = s1; red[w][quad * 4 + r][1] = s2; }
        }
        __syncthreads();
        #pragma unroll
        for (int r = 0; r < 4; r++) {
            int rr = quad * 4 + r;
            float t1 = 0.f, t2 = 0.f;
            #pragma unroll
            for (int ww = 0; ww < 8; ww++) { t1 += red[ww][rr][0]; t2 += red[ww][rr][1]; }
            float mu = t1 * (1.0f / 256.0f);
            float var = t2 * (1.0f / 256.0f) - mu * mu;
            float rstd = rsqrtf(var + 1e-5f);
            #pragma unroll
            for (int nj = 0; nj < 2; nj++) {
                int col = w * 32 + nj * 16 + lrow;
                float t = (v[nj][r] - mu) * rstd * g1[col] + b1[col];
                if (gelu1) t = gelu_exact(t);
                v[nj][r] = t;
            }
        }
        __syncthreads();
    } else if (gelu1) {
        #pragma unroll
        for (int nj = 0; nj < 2; nj++)
            #pragma unroll
            for (int r = 0; r < 4; r++)
                v[nj][r] = gelu_exact(v[nj][r]);
    }

    if (outF) {
        #pragma unroll
        for (int nj = 0; nj < 2; nj++) {
            int col = w * 32 + nj * 16 + lrow;
            #pragma unroll
            for (int r = 0; r < 4; r++)
                outF[(size_t)(m0 + quad * 4 + r) * 256 + col] = v[nj][r];
        }
    }

    if (l2out) {
        #pragma unroll
        for (int r = 0; r < 4; r++) {
            float s2 = v[0][r]*v[0][r] + v[1][r]*v[1][r];
            s2 = row_sum16(s2);
            if (lrow == 0) red[w][quad * 4 + r][0] = s2;
        }
        __syncthreads();
        if (tid < 16) {
            float t = 0.f;
            #pragma unroll
            for (int ww = 0; ww < 8; ww++) t += red[ww][tid][0];
            sq[tid] = sqrtf(t);
        }
        __syncthreads();
        if (tid == 0) {
            float a = 0.f;
            #pragma unroll
            for (int i = 0; i < 16; i++) a += sq[i];
            atomicAdd(l2out, a * (0.01f / 4096.0f));
        }
    }

    if (g2) {
        __syncthreads();
        #pragma unroll
        for (int r = 0; r < 4; r++) {
            float s1 = v[0][r] + v[1][r];
            float s2 = v[0][r]*v[0][r] + v[1][r]*v[1][r];
            s1 = row_sum16(s1); s2 = row_sum16(s2);
            if (lrow == 0) { red[w][quad * 4 + r][0] = s1; red[w][quad * 4 + r][1] = s2; }
        }
        __syncthreads();
        #pragma unroll
        for (int r = 0; r < 4; r++) {
            int rr = quad * 4 + r;
            float t1 = 0.f, t2 = 0.f;
            #pragma unroll
            for (int ww = 0; ww < 8; ww++) { t1 += red[ww][rr][0]; t2 += red[ww][rr][1]; }
            float mu = t1 * (1.0f / 256.0f);
            float var = t2 * (1.0f / 256.0f) - mu * mu;
            float rstd = rsqrtf(var + 1e-5f);
            #pragma unroll
            for (int nj = 0; nj < 2; nj++) {
                int col = w * 32 + nj * 16 + lrow;
                outB[(size_t)(m0 + rr) * 256 + col] = bf16bits((v[nj][r] - mu) * rstd * g2[col] + b2[col]);
            }
        }
    } else if (outB) {
        #pragma unroll
        for (int nj = 0; nj < 2; nj++) {
            int col = w * 32 + nj * 16 + lrow;
            #pragma unroll
            for (int r = 0; r < 4; r++)
                outB[(size_t)(m0 + quad * 4 + r) * 256 + col] = bf16bits(v[nj][r]);
        }
    }

    // ---- fused cls GEMM: logits(16 x 128) = v(16 x 256) @ clsW(128 x 256)^T ----
    if (clsW) {
        #pragma unroll
        for (int nj = 0; nj < 2; nj++) {
            int col = w * 32 + nj * 16 + lrow;
            #pragma unroll
            for (int r = 0; r < 4; r++)
                hb[quad * 4 + r][col] = bf16bits(v[nj][r]);
        }
        __syncthreads();
        f32x4 cacc = {};
        #pragma unroll
        for (int k0 = 0; k0 < 256; k0 += 32) {
            frag8 a = *reinterpret_cast<const frag8*>(&hb[lrow][k0 + quad * 8]);
            frag8 b = *reinterpret_cast<const frag8*>(clsW + (size_t)(w * 16 + lrow) * 256 + k0 + quad * 8);
            cacc = __builtin_amdgcn_mfma_f32_16x16x32_bf16(a, b, cacc, 0, 0, 0);
        }
        int col = w * 16 + lrow;
        float cb = clsB[col];
        #pragma unroll
        for (int r = 0; r < 4; r++)
            clsOut[(size_t)(m0 + quad * 4 + r) * 128 + col] = cacc[r] + cb;
    }
}

// ---------------- chunked selective scan (unchanged from round 8 — control) -----
__global__ __launch_bounds__(1024)
void scan_chunked(const float* __restrict__ xdt,
                  const float* __restrict__ dtw, const float* __restrict__ dtb,
                  const float* __restrict__ ucT,
                  const float* __restrict__ BT, const float* __restrict__ CT,
                  const unsigned short* __restrict__ szT,
                  const float* __restrict__ Ac,
                  const float* __restrict__ Dp,
                  unsigned short* __restrict__ y)
{
    __shared__ float aprod_s[16][64];
    __shared__ float sfin_s[16][64];
    __shared__ float sin_w[16][64];
    __shared__ __align__(16) float ylocal[16][64][4];
    __shared__ __align__(16) float dltS[4][1032];
    __shared__ __align__(16) float ucS[4][1032];

    const int j = blockIdx.x;
    const int bid = (j & 7) * 64 + (j >> 3);     // XCD swizzle
    const int b = bid >> 7;
    const int d0 = (bid & 127) * 4;
    const int w = threadIdx.x >> 6;
    const int lane = threadIdx.x & 63;
    const int dsub = lane >> 4, s = lane & 15;
    const int d = d0 + dsub;
    const int t = w * 64 + lane;

    const float Acoef = Ac[d * 16 + s];          // already * log2(e)

    const float4* Bp = reinterpret_cast<const float4*>(BT + ((size_t)(b * 16 + s)) * 1024 + w * 64);
    const float4* Cp = reinterpret_cast<const float4*>(CT + ((size_t)(b * 16 + s)) * 1024 + w * 64);

    // ---- issue long-latency loads first: uc stage, xdt, B/C tile 0, sz ----
    {
        int dd = lane >> 4, tq = (lane & 15) * 4;
        float4 v = *reinterpret_cast<const float4*>(ucT + ((size_t)(b * 512 + d0 + dd)) * 1024 + w * 64 + tq);
        *reinterpret_cast<float4*>(&ucS[dd][w * 64 + tq]) = v;
    }
    const float* xr = xdt + ((size_t)(b * 1024) + t) * 16;
    float4 x0 = *reinterpret_cast<const float4*>(xr + 0);
    float4 x1 = *reinterpret_cast<const float4*>(xr + 4);
    float4 x2 = *reinterpret_cast<const float4*>(xr + 8);
    float4 x3 = *reinterpret_cast<const float4*>(xr + 12);
    float4 B4 = Bp[0], C4 = Cp[0];
    unsigned short szr[4];
    #pragma unroll
    for (int dd = 0; dd < 4; dd++)
        szr[dd] = szT[((size_t)(b * 512 + d0 + dd)) * 1024 + t];

    // ---- front-end: compute dlt for own chunk (lane = t) ----
    #pragma unroll
    for (int dd = 0; dd < 4; dd++) {
        const float* wt = dtw + (size_t)(d0 + dd) * 16;
        float a2 = dtb[d0 + dd]
            + x0.x * wt[0]  + x0.y * wt[1]  + x0.z * wt[2]  + x0.w * wt[3]
            + x1.x * wt[4]  + x1.y * wt[5]  + x1.z * wt[6]  + x1.w * wt[7]
            + x2.x * wt[8]  + x2.y * wt[9]  + x2.z * wt[10] + x2.w * wt[11]
            + x3.x * wt[12] + x3.y * wt[13] + x3.z * wt[14] + x3.w * wt[15];
        dltS[dd][t] = softplus_f(a2);
    }

    // ---- Phase A: local scan (B/C + dt/ut 1-deep prefetch; per-jj y stores) ----
    float st = 0.0f, ap = 1.0f;
    float4 dt4 = *reinterpret_cast<const float4*>(&dltS[dsub][w * 64]);
    float4 ut4 = *reinterpret_cast<const float4*>(&ucS[dsub][w * 64]);
    #pragma unroll
    for (int q = 0; q < 16; q++) {
        float4 nB, nC, ndt, nut;
        if (q < 15) {
            nB = Bp[q + 1]; nC = Cp[q + 1];
            ndt = *reinterpret_cast<const float4*>(&dltS[dsub][w * 64 + (q + 1) * 4]);
            nut = *reinterpret_cast<const float4*>(&ucS[dsub][w * 64 + (q + 1) * 4]);
        }
        const float* dtp = (const float*)&dt4;
        const float* utp = (const float*)&ut4;
        const float* Btp = (const float*)&B4;
        const float* Ctp = (const float*)&C4;
        #pragma unroll
        for (int jj = 0; jj < 4; jj++) {
            float dA = exp2_raw(dtp[jj] * Acoef);
            st = st * dA + dtp[jj] * utp[jj] * Btp[jj];
            ap *= dA;
            float part = row_sum16(st * Ctp[jj]);
            if (s == 0) ylocal[w][q * 4 + jj][dsub] = part;
        }
        B4 = nB; C4 = nC; dt4 = ndt; ut4 = nut;
    }
    aprod_s[w][lane] = ap;
    sfin_s[w][lane] = st;
    __syncthreads();                                 // the only barrier

    // ---- decentralized combine ----
    {
        float pre = 0.0f;
        #pragma unroll
        for (int c = 0; c < 15; c++) {
            float apc = aprod_s[c][lane];
            float sfc = sfin_s[c][lane];
            float cand = sfc + apc * pre;
            pre = (c < w) ? cand : pre;
        }
        sin_w[w][lane] = pre;
    }

    // ---- Phase C: lane = t; correction via prefix sums + epilogue ----
    float cums[4];
    #pragma unroll
    for (int dd = 0; dd < 4; dd++)
        cums[dd] = dltS[dd][t];
    #pragma unroll
    for (int dd = 0; dd < 4; dd++)
        cums[dd] = prefix_sum64(cums[dd]);

    float4 yl = *reinterpret_cast<const float4*>(&ylocal[w][lane][0]);
    float acc[4] = { yl.x, yl.y, yl.z, yl.w };

    float Cs[4];
    #pragma unroll
    for (int jj = 0; jj < 4; jj++)
        Cs[jj] = CT[((size_t)(b * 16 + jj)) * 1024 + t];
    #pragma unroll
    for (int sq = 0; sq < 4; sq++) {
        float Csn[4];
        if (sq < 3) {
            #pragma unroll
            for (int jj = 0; jj < 4; jj++)
                Csn[jj] = CT[((size_t)(b * 16 + (sq + 1) * 4 + jj)) * 1024 + t];
        }
        #pragma unroll
        for (int dd = 0; dd < 4; dd++) {
            float4 sin4 = *reinterpret_cast<const float4*>(&sin_w[w][dd * 16 + sq * 4]);
            const float* sp = (const float*)&sin4;
            #pragma unroll
            for (int jj = 0; jj < 4; jj++) {
                float ac = Ac[(d0 + dd) * 16 + sq * 4 + jj];      // already * log2(e)
                acc[dd] += sp[jj] * Cs[jj] * exp2_raw(ac * cums[dd]);
            }
        }
        #pragma unroll
        for (int jj = 0; jj < 4; jj++) Cs[jj] = Csn[jj];
    }

    const size_t row = (size_t)b * 1024 + t;
    ushort4 yo;
    {
        float ut0 = ucS[0][t], ut1 = ucS[1][t], ut2 = ucS[2][t], ut3 = ucS[3][t];
        float y0 = (acc[0] + ut0 * Dp[d0 + 0]) * bf2f(szr[0]);
        float y1 = (acc[1] + ut1 * Dp[d0 + 1]) * bf2f(szr[1]);
        float y2 = (acc[2] + ut2 * Dp[d0 + 2]) * bf2f(szr[2]);
        float y3 = (acc[3] + ut3 * Dp[d0 + 3]) * bf2f(szr[3]);
        yo.x = bf16bits(y0); yo.y = bf16bits(y1);
        yo.z = bf16bits(y2); yo.w = bf16bits(y3);
    }
    *reinterpret_cast<ushort4*>(y + row * 512 + d0) = yo;
}

// ---------------- launcher ----------------
extern "C" void kernel_launch(void* const* d_in, const int* in_sizes, int n_in,
                              void* d_out, int out_size, void* d_ws, size_t ws_size,
                              hipStream_t stream)
{
    const float* x      = (const float*)d_in[0];
    const float* in_b   = (const float*)d_in[2];
    const float* ln_g   = (const float*)d_in[3];
    const float* ln_b   = (const float*)d_in[4];
    const float* blk_ng  = (const float*)d_in[5];
    const float* blk_nb  = (const float*)d_in[6];
    const float* blk_cw  = (const float*)d_in[8];
    const float* blk_cb  = (const float*)d_in[9];
    const float* blk_dtw = (const float*)d_in[11];
    const float* blk_dtb = (const float*)d_in[12];
    const float* blk_Alog= (const float*)d_in[13];
    const float* blk_D   = (const float*)d_in[14];
    const float* op_b   = (const float*)d_in[17];
    const float* cls_b  = (const float*)d_in[19];
    float* out = (float*)d_out;

    const int BL = 4096;
    float* ws = (float*)d_ws;
    float* h0   = ws;                         // 1,048,576
    float* xzuT = h0 + 1048576;               // 2,097,152  [b][d][t] fp32 (u pre-conv)
    float* ucT  = xzuT + 2097152;             // 2,097,152  [b][d][t]
    float* xdt  = ucT + 2097152;              // 131,072 (2 layers x 4096x16)
    float* BT   = xdt + 131072;               // 131,072 (2 layers x [b][s][t])
    float* CT   = BT + 131072;                // 131,072
    float* Ac   = CT + 131072;                // 16,384
    unsigned short* szT = (unsigned short*)(Ac + 16384);  // 2,097,152 bf16 [b][d][t]
    unsigned short* wb  = szT + 2097152;      // 1,130,496
    unsigned short* hnb = wb + 1130496;       // 1,048,576
    unsigned short* ybb = hnb + 1048576;      // 2,097,152
    unsigned short* h0b = hnb;
    unsigned short* in_wb  = wb;
    unsigned short* ipw_b  = wb + 196608;
    unsigned short* xpw_b  = wb + 720896;
    unsigned short* opw_b  = wb + 770048;
    unsigned short* op_wb  = wb + 1032192;
    unsigned short* cls_wb = wb + 1097728;

    CvtArgs ca;
    ca.src[0] = (const float*)d_in[1];  ca.dst[0] = in_wb;  ca.n4[0] = 196608 / 4;
    ca.src[1] = (const float*)d_in[7];  ca.dst[1] = ipw_b;  ca.n4[1] = 524288 / 4;
    ca.src[2] = (const float*)d_in[10]; ca.dst[2] = xpw_b;  ca.n4[2] = 49152 / 4;
    ca.src[3] = (const float*)d_in[15]; ca.dst[3] = opw_b;  ca.n4[3] = 262144 / 4;
    ca.src[4] = (const float*)d_in[16]; ca.dst[4] = op_wb;  ca.n4[4] = 65536 / 4;
    ca.src[5] = (const float*)d_in[18]; ca.dst[5] = cls_wb; ca.n4[5] = 32768 / 4;
    int total4 = 1130496 / 4;
    int zquads = 393216 / 4;                  // xdt+BT+CT (both layers, contiguous)
    int totalg = total4 + 16384 + zquads;
    cvt_all<<<(totalg + 255) / 256, 256, 0, stream>>>(ca, total4, blk_Alog, Ac,
                                                      xdt, zquads,
                                                      out + (size_t)BL * 128);

    // in_proj (A from fp32 x) + bias + LN + GELU -> h0 (fp32), + LN(layer0) -> hnb
    rowgemm<<<256, 512, 0, stream>>>(nullptr, x, in_wb, in_b, nullptr,
                                     ln_g, ln_b, 1,
                                     blk_ng, blk_nb,
                                     h0, hnb, nullptr,
                                     nullptr, nullptr, nullptr, 768);

    for (int l = 0; l < 2; l++) {
        const float* cw   = blk_cw  + (size_t)l * 512 * 4;
        const float* cb   = blk_cb  + l * 512;
        const float* dtw  = blk_dtw + (size_t)l * 512 * 16;
        const float* dtb  = blk_dtb + l * 512;
        const float* Dl   = blk_D   + l * 512;
        const unsigned short* ipwl = ipw_b + (size_t)l * 262144;
        const unsigned short* xpwl = xpw_b + (size_t)l * 24576;
        const unsigned short* opwl = opw_b + (size_t)l * 131072;
        float* xdtl = xdt + (size_t)l * 65536;
        float* BTl  = BT  + (size_t)l * 65536;
        float* CTl  = CT  + (size_t)l * 65536;

        // ipw GEMM: u -> xzuT fp32 [b][d][t]; z -> silu(z) bf16 szT [b][d][t]
        gemm_ipw<<<dim3(16, 64), 256, 0, stream>>>(hnb, ipwl, xzuT, szT);
        // fused conv + xpw projection (K-split x4): ucT + atomic xdt/BT/CT
        gemm_cat<<<dim3(4, 64), 256, 0, stream>>>(xzuT, xpwl, cw, cb, ucT, xdtl, BTl, CTl);
        // scan (computes dlt from xdt in-kernel) -> ybb
        scan_chunked<<<512, 1024, 0, stream>>>(xdtl, dtw, dtb, ucT, BTl, CTl, szT,
                                               Ac + (size_t)l * 8192, Dl, ybb);
        // h0 += ybb @ opw.T; layer0: +LN(layer1)->hnb; layer1: ->h0b bf16 only
        if (l == 0)
            rowgemm<<<256, 512, 0, stream>>>(ybb, nullptr, opwl, nullptr, h0,
                                             nullptr, nullptr, 0,
                                             blk_ng + 256, blk_nb + 256,
                                             h0, hnb, nullptr,
                                             nullptr, nullptr, nullptr, 512);
        else
            rowgemm<<<256, 512, 0, stream>>>(ybb, nullptr, opwl, nullptr, h0,
                                             nullptr, nullptr, 0,
                                             nullptr, nullptr,
                                             nullptr, h0b, nullptr,
                                             nullptr, nullptr, nullptr, 512);
    }

    // final: h2 = gelu(h0b @ op_w.T + op_b); fused L2 scalar + cls GEMM -> out
    rowgemm<<<256, 512, 0, stream>>>(h0b, nullptr, op_wb, op_b, nullptr,
                                     nullptr, nullptr, 1,
                                     nullptr, nullptr,
                                     nullptr, nullptr, out + (size_t)BL * 128,
                                     cls_wb, cls_b, out, 256);
}

// Round 10
// 276.018 us; speedup vs baseline: 1.1400x; 1.0201x over previous
//
#include <hip/hip_runtime.h>
#include <hip/hip_bf16.h>
#include <math.h>

typedef __attribute__((ext_vector_type(8))) short frag8;   // 8 bf16 (4 VGPRs)
typedef __attribute__((ext_vector_type(4))) float f32x4;

// ---------------- device helpers ----------------
__device__ __forceinline__ float gelu_exact(float x) {
    return 0.5f * x * (1.0f + erff(x * 0.70710678118654752f));
}
// raw v_exp_f32 (2^x, flush-to-zero)
__device__ __forceinline__ float exp2_raw(float x) {
    return __builtin_amdgcn_exp2f(x);
}
// softplus via native exp2/log2: log(1+e^x) = log2(1+2^(x*log2e)) * ln2
__device__ __forceinline__ float softplus_f(float x) {
    float e = exp2_raw(x * 1.4426950408889634f);
    float sp = __log2f(1.0f + e) * 0.6931471805599453f;
    return (x > 20.0f) ? x : sp;
}
__device__ __forceinline__ float sigmoid_f(float x) {
    return 1.0f / (1.0f + __expf(-x));
}
__device__ __forceinline__ unsigned short bf16bits(float x) {
    __hip_bfloat16 h = __float2bfloat16(x);
    return *(unsigned short*)&h;
}
__device__ __forceinline__ float bf2f(unsigned short u) {
    unsigned int v = ((unsigned int)u) << 16;
    return __builtin_bit_cast(float, v);
}
// sum over the 16 lanes of each DPP row-of-16 — VALU-pipe only
__device__ __forceinline__ float row_sum16(float x) {
    int t;
    t = __builtin_amdgcn_update_dpp(0, __builtin_bit_cast(int, x), 0x128, 0xf, 0xf, true); // row_ror:8
    x += __builtin_bit_cast(float, t);
    t = __builtin_amdgcn_update_dpp(0, __builtin_bit_cast(int, x), 0x124, 0xf, 0xf, true); // row_ror:4
    x += __builtin_bit_cast(float, t);
    t = __builtin_amdgcn_update_dpp(0, __builtin_bit_cast(int, x), 0x122, 0xf, 0xf, true); // row_ror:2
    x += __builtin_bit_cast(float, t);
    t = __builtin_amdgcn_update_dpp(0, __builtin_bit_cast(int, x), 0x121, 0xf, 0xf, true); // row_ror:1
    x += __builtin_bit_cast(float, t);
    return x;
}
// inclusive prefix sum over the full 64-lane wave (DPP, VALU-pipe only)
__device__ __forceinline__ float prefix_sum64(float x) {
    int t;
    t = __builtin_amdgcn_update_dpp(0, __builtin_bit_cast(int, x), 0x111, 0xf, 0xf, true); // row_shr:1
    x += __builtin_bit_cast(float, t);
    t = __builtin_amdgcn_update_dpp(0, __builtin_bit_cast(int, x), 0x112, 0xf, 0xf, true); // row_shr:2
    x += __builtin_bit_cast(float, t);
    t = __builtin_amdgcn_update_dpp(0, __builtin_bit_cast(int, x), 0x114, 0xf, 0xf, true); // row_shr:4
    x += __builtin_bit_cast(float, t);
    t = __builtin_amdgcn_update_dpp(0, __builtin_bit_cast(int, x), 0x118, 0xf, 0xf, true); // row_shr:8
    x += __builtin_bit_cast(float, t);
    t = __builtin_amdgcn_update_dpp(0, __builtin_bit_cast(int, x), 0x142, 0xa, 0xf, true); // row_bcast:15
    x += __builtin_bit_cast(float, t);
    t = __builtin_amdgcn_update_dpp(0, __builtin_bit_cast(int, x), 0x143, 0xc, 0xf, true); // row_bcast:31
    x += __builtin_bit_cast(float, t);
    return x;
}

// -------- fp32->bf16 weight cvt + Acoef + l2 zero + zero xdt/BT/CT (both layers)
struct CvtArgs {
    const float* src[6];
    unsigned short* dst[6];
    int n4[6];
};
__global__ __launch_bounds__(256)
void cvt_all(CvtArgs a, int total4, const float* __restrict__ Alog,
             float* __restrict__ Ac, float* __restrict__ Z, int zquads, float* l2)
{
    int i = blockIdx.x * 256 + threadIdx.x;
    if (i >= total4) {
        int j = i - total4;
        if (j < 16384) {
            Ac[j] = -__expf(Alog[j]) * 1.4426950408889634f;
        } else {
            int z = j - 16384;
            if (z < zquads) {
                float4 zero = {0.f, 0.f, 0.f, 0.f};
                reinterpret_cast<float4*>(Z)[z] = zero;
            }
        }
        if (j == 0) *l2 = 0.0f;
        return;
    }
    int seg = 0;
    while (i >= a.n4[seg]) { i -= a.n4[seg]; seg++; }
    float4 v = reinterpret_cast<const float4*>(a.src[seg])[i];
    ushort4 o;
    o.x = bf16bits(v.x); o.y = bf16bits(v.y); o.z = bf16bits(v.z); o.w = bf16bits(v.w);
    reinterpret_cast<ushort4*>(a.dst[seg])[i] = o;
}

// ---------------- ipw GEMM (N=1024, K=256): u-half -> xzuT fp32 [b][d][t],
// ---------------- z-half -> silu(z) bf16 szT [b][d][t] ----------------
// BK=128: 2 stage+barrier iterations for K=256
__global__ __launch_bounds__(256)
void gemm_ipw(const unsigned short* __restrict__ A,
              const unsigned short* __restrict__ W,
              float* __restrict__ xzuT,
              unsigned short* __restrict__ szT)
{
    __shared__ __align__(16) unsigned short As[64][136];
    __shared__ __align__(16) unsigned short Bs[64][136];

    const int tid = threadIdx.x;
    const int wid = tid >> 6, lane = tid & 63;
    const int wm = (wid >> 1) * 32, wn = (wid & 1) * 32;
    const int m0 = blockIdx.y * 64, n0 = blockIdx.x * 64;
    const int lrow = lane & 15, quad = lane >> 4;
    const int K = 256;

    const int sm = tid >> 2;
    const int sk = (tid & 3) * 32;

    f32x4 acc[2][2] = {};

    for (int k0 = 0; k0 < K; k0 += 128) {
        #pragma unroll
        for (int q = 0; q < 4; q++) {
            *reinterpret_cast<float4*>(&As[sm][sk + q * 8]) =
                *reinterpret_cast<const float4*>(A + (size_t)(m0 + sm) * K + k0 + sk + q * 8);
            *reinterpret_cast<float4*>(&Bs[sm][sk + q * 8]) =
                *reinterpret_cast<const float4*>(W + (size_t)(n0 + sm) * K + k0 + sk + q * 8);
        }
        __syncthreads();

        #pragma unroll
        for (int h = 0; h < 4; h++) {
            frag8 a0 = *reinterpret_cast<const frag8*>(&As[wm + lrow][h * 32 + quad * 8]);
            frag8 a1 = *reinterpret_cast<const frag8*>(&As[wm + 16 + lrow][h * 32 + quad * 8]);
            frag8 b0 = *reinterpret_cast<const frag8*>(&Bs[wn + lrow][h * 32 + quad * 8]);
            frag8 b1 = *reinterpret_cast<const frag8*>(&Bs[wn + 16 + lrow][h * 32 + quad * 8]);

            acc[0][0] = __builtin_amdgcn_mfma_f32_16x16x32_bf16(a0, b0, acc[0][0], 0, 0, 0);
            acc[0][1] = __builtin_amdgcn_mfma_f32_16x16x32_bf16(a0, b1, acc[0][1], 0, 0, 0);
            acc[1][0] = __builtin_amdgcn_mfma_f32_16x16x32_bf16(a1, b0, acc[1][0], 0, 0, 0);
            acc[1][1] = __builtin_amdgcn_mfma_f32_16x16x32_bf16(a1, b1, acc[1][1], 0, 0, 0);
        }
        __syncthreads();
    }

    const int bb = m0 >> 10;
    const int tb = m0 & 1023;
    #pragma unroll
    for (int mi = 0; mi < 2; mi++) {
        int t4 = tb + wm + mi * 16 + quad * 4;
        #pragma unroll
        for (int nj = 0; nj < 2; nj++) {
            int col = n0 + wn + nj * 16 + lrow;
            if (col < 512) {
                float4 o = { acc[mi][nj][0], acc[mi][nj][1], acc[mi][nj][2], acc[mi][nj][3] };
                *reinterpret_cast<float4*>(xzuT + ((size_t)(bb * 512 + col)) * 1024 + t4) = o;
            } else {
                int z = col - 512;
                ushort4 o;
                float v0 = acc[mi][nj][0], v1 = acc[mi][nj][1], v2 = acc[mi][nj][2], v3 = acc[mi][nj][3];
                o.x = bf16bits(v0 * sigmoid_f(v0));
                o.y = bf16bits(v1 * sigmoid_f(v1));
                o.z = bf16bits(v2 * sigmoid_f(v2));
                o.w = bf16bits(v3 * sigmoid_f(v3));
                *reinterpret_cast<ushort4*>(szT + ((size_t)(bb * 512 + z)) * 1024 + t4) = o;
            }
        }
    }
}

// ---------------- conv4+SiLU fused into xpw projection, K-split x4 --------------
// BK=128: SINGLE stage + one barrier
__global__ __launch_bounds__(256)
void gemm_cat(const float* __restrict__ xzuT,
              const unsigned short* __restrict__ W,     // xpw: 48 x 512 bf16
              const float* __restrict__ cw, const float* __restrict__ cb,
              float* __restrict__ ucT,
              float* __restrict__ xdt, float* __restrict__ BT, float* __restrict__ CT)
{
    __shared__ __align__(16) unsigned short As[64][136];
    __shared__ __align__(16) unsigned short Bs[64][136];

    const int tid = threadIdx.x;
    const int wid = tid >> 6, lane = tid & 63;
    const int wm = (wid >> 1) * 32, wn = (wid & 1) * 32;
    const int kc = blockIdx.x;            // 0..3 (128-d chunk)
    const int m0 = blockIdx.y * 64;
    const int bb = m0 >> 10;
    const int tb = m0 & 1023;
    const int lrow = lane & 15, quad = lane >> 4;
    const int N = 48;

    const int sm = tid >> 2;
    const int sk = (tid & 3) * 32;

    f32x4 acc[2][2] = {};

    {
        #pragma unroll
        for (int p = 0; p < 8; p++) {
            int kk = (tid >> 4) + p * 16;
            int k  = kc * 128 + kk;
            int mq = tid & 15;
            int tg = tb + mq * 4;
            const float* rowp = xzuT + ((size_t)(bb * 512 + k)) * 1024;
            float4 cur = *reinterpret_cast<const float4*>(rowp + tg);
            float4 prev = {0.f, 0.f, 0.f, 0.f};
            if (tg != 0) prev = *reinterpret_cast<const float4*>(rowp + tg - 4);
            float4 cv = *reinterpret_cast<const float4*>(cw + k * 4);
            float cbv = cb[k];
            float o0 = cbv + cv.x*prev.y + cv.y*prev.z + cv.z*prev.w + cv.w*cur.x;
            float o1 = cbv + cv.x*prev.z + cv.y*prev.w + cv.z*cur.x  + cv.w*cur.y;
            float o2 = cbv + cv.x*prev.w + cv.y*cur.x  + cv.z*cur.y  + cv.w*cur.z;
            float o3 = cbv + cv.x*cur.x  + cv.y*cur.y  + cv.z*cur.z  + cv.w*cur.w;
            o0 *= sigmoid_f(o0); o1 *= sigmoid_f(o1);
            o2 *= sigmoid_f(o2); o3 *= sigmoid_f(o3);
            float4 uo = { o0, o1, o2, o3 };
            *reinterpret_cast<float4*>(ucT + ((size_t)(bb * 512 + k)) * 1024 + tg) = uo;
            As[mq * 4 + 0][kk] = bf16bits(o0);
            As[mq * 4 + 1][kk] = bf16bits(o1);
            As[mq * 4 + 2][kk] = bf16bits(o2);
            As[mq * 4 + 3][kk] = bf16bits(o3);
        }
        #pragma unroll
        for (int q = 0; q < 4; q++) {
            float4 bv = {0.f, 0.f, 0.f, 0.f};
            if (sm < N) bv = *reinterpret_cast<const float4*>(W + (size_t)sm * 512 + kc * 128 + sk + q * 8);
            *reinterpret_cast<float4*>(&Bs[sm][sk + q * 8]) = bv;
        }
        __syncthreads();

        #pragma unroll
        for (int h = 0; h < 4; h++) {
            frag8 a0 = *reinterpret_cast<const frag8*>(&As[wm + lrow][h * 32 + quad * 8]);
            frag8 a1 = *reinterpret_cast<const frag8*>(&As[wm + 16 + lrow][h * 32 + quad * 8]);
            frag8 b0 = *reinterpret_cast<const frag8*>(&Bs[wn + lrow][h * 32 + quad * 8]);
            frag8 b1 = *reinterpret_cast<const frag8*>(&Bs[wn + 16 + lrow][h * 32 + quad * 8]);

            acc[0][0] = __builtin_amdgcn_mfma_f32_16x16x32_bf16(a0, b0, acc[0][0], 0, 0, 0);
            acc[0][1] = __builtin_amdgcn_mfma_f32_16x16x32_bf16(a0, b1, acc[0][1], 0, 0, 0);
            acc[1][0] = __builtin_amdgcn_mfma_f32_16x16x32_bf16(a1, b0, acc[1][0], 0, 0, 0);
            acc[1][1] = __builtin_amdgcn_mfma_f32_16x16x32_bf16(a1, b1, acc[1][1], 0, 0, 0);
        }
    }

    #pragma unroll
    for (int mi = 0; mi < 2; mi++) {
        #pragma unroll
        for (int nj = 0; nj < 2; nj++) {
            int col = wn + nj * 16 + lrow;
            if (col >= N) continue;
            #pragma unroll
            for (int r = 0; r < 4; r++) {
                int trow = tb + wm + mi * 16 + quad * 4 + r;     // t within batch
                float v = acc[mi][nj][r];
                if (col < 16)
                    atomicAdd(&xdt[((size_t)(bb * 1024 + trow)) * 16 + col], v);
                else if (col < 32)
                    atomicAdd(&BT[((size_t)(bb * 16 + col - 16)) * 1024 + trow], v);
                else
                    atomicAdd(&CT[((size_t)(bb * 16 + col - 32)) * 1024 + trow], v);
            }
        }
    }
}

// ---------------- full-row GEMM (N=256), 512 threads / 8 waves ------------------
// BK=128 staging
__global__ __launch_bounds__(512)
void rowgemm(const unsigned short* __restrict__ A,
             const float* __restrict__ Af,
             const unsigned short* __restrict__ W,
             const float* __restrict__ bias,
             const float* res,
             const float* g1, const float* b1, int gelu1,
             const float* g2, const float* b2,
             float* outF, unsigned short* outB, float* l2out,
             const unsigned short* clsW, const float* clsB, float* clsOut,
             int K)
{
    __shared__ __align__(16) unsigned short As[16][136];
    __shared__ __align__(16) unsigned short Bs[256][136];
    __shared__ float red[8][16][2];
    __shared__ float sq[16];
    __shared__ __align__(16) unsigned short hb[16][264];

    const int tid = threadIdx.x;
    const int w = tid >> 6, lane = tid & 63;
    const int lrow = lane & 15, quad = lane >> 4;
    const int m0 = blockIdx.x * 16;

    f32x4 acc[2] = {};

    for (int k0 = 0; k0 < K; k0 += 128) {
        if (tid < 64) {
            int r_ = tid >> 2, c32 = (tid & 3) * 32;
            if (Af) {
                const float* src = Af + (size_t)(m0 + r_) * K + k0 + c32;
                unsigned short* dst = &As[r_][c32];
                #pragma unroll
                for (int q = 0; q < 8; q++) {
                    float4 v = *reinterpret_cast<const float4*>(src + q * 4);
                    dst[q * 4 + 0] = bf16bits(v.x);
                    dst[q * 4 + 1] = bf16bits(v.y);
                    dst[q * 4 + 2] = bf16bits(v.z);
                    dst[q * 4 + 3] = bf16bits(v.w);
                }
            } else {
                #pragma unroll
                for (int q = 0; q < 4; q++)
                    *reinterpret_cast<float4*>(&As[r_][c32 + q * 8]) =
                        *reinterpret_cast<const float4*>(A + (size_t)(m0 + r_) * K + k0 + c32 + q * 8);
            }
        }
        {
            int c32 = (tid & 3) * 32;
            #pragma unroll
            for (int i = 0; i < 2; i++) {
                int n = (tid >> 2) + i * 128;
                #pragma unroll
                for (int q = 0; q < 4; q++)
                    *reinterpret_cast<float4*>(&Bs[n][c32 + q * 8]) =
                        *reinterpret_cast<const float4*>(W + (size_t)n * K + k0 + c32 + q * 8);
            }
        }
        __syncthreads();
        #pragma unroll
        for (int h = 0; h < 4; h++) {
            frag8 a = *reinterpret_cast<const frag8*>(&As[lrow][h * 32 + quad * 8]);
            #pragma unroll
            for (int nj = 0; nj < 2; nj++) {
                frag8 b = *reinterpret_cast<const frag8*>(&Bs[w * 32 + nj * 16 + lrow][h * 32 + quad * 8]);
                acc[nj] = __builtin_amdgcn_mfma_f32_16x16x32_bf16(a, b, acc[nj], 0, 0, 0);
            }
        }
        __syncthreads();
    }

    float v[2][4];
    #pragma unroll
    for (int nj = 0; nj < 2; nj++) {
        int col = w * 32 + nj * 16 + lrow;
        #pragma unroll
        for (int r = 0; r < 4; r++) {
            int row = m0 + quad * 4 + r;
            float t = acc[nj][r];
            if (bias) t += bias[col];
            if (res) t += res[(size_t)row * 256 + col];
            v[nj][r] = t;
        }
    }

    if (g1) {
        #pragma unroll
        for (int r = 0; r < 4; r++) {
            float s1 = v[0][r] + v[1][r];
            float s2 = v[0][r]*v[0][r] + v[1][r]*v[1][r];
            s1 = row_sum16(s1); s2 = row_sum16(s2);
            if (lrow == 0) { red[w][quad * 4 + r][0] = s1; red[w][quad * 4 + r][1] = s2; }
        }
        __syncthreads();
        #pragma unroll
        for (int r = 0; r < 4; r++) {
            int rr = quad * 4 + r;
            float t1 = 0.f, t2 = 0.f;
            #pragma unroll
            for (int ww = 0; ww < 8; ww++) { t1 += red[ww][rr][0]; t2 += red[ww][rr][1]; }
            float mu = t1 * (1.0f / 256.0f);
            float var = t2 * (1.0f / 256.0f) - mu * mu;
            float rstd = rsqrtf(var + 1e-5f);
            #pragma unroll
            for (int nj = 0; nj < 2; nj++) {
                int col = w * 32 + nj * 16 + lrow;
                float t = (v[nj][r] - mu) * rstd * g1[col] + b1[col];
                if (gelu1) t = gelu_exact(t);
                v[nj][r] = t;
            }
        }
        __syncthreads();
    } else if (gelu1) {
        #pragma unroll
        for (int nj = 0; nj < 2; nj++)
            #pragma unroll
            for (int r = 0; r < 4; r++)
                v[nj][r] = gelu_exact(v[nj][r]);
    }

    if (outF) {
        #pragma unroll
        for (int nj = 0; nj < 2; nj++) {
            int col = w * 32 + nj * 16 + lrow;
            #pragma unroll
            for (int r = 0; r < 4; r++)
                outF[(size_t)(m0 + quad * 4 + r) * 256 + col] = v[nj][r];
        }
    }

    if (l2out) {
        #pragma unroll
        for (int r = 0; r < 4; r++) {
            float s2 = v[0][r]*v[0][r] + v[1][r]*v[1][r];
            s2 = row_sum16(s2);
            if (lrow == 0) red[w][quad * 4 + r][0] = s2;
        }
        __syncthreads();
        if (tid < 16) {
            float t = 0.f;
            #pragma unroll
            for (int ww = 0; ww < 8; ww++) t += red[ww][tid][0];
            sq[tid] = sqrtf(t);
        }
        __syncthreads();
        if (tid == 0) {
            float a = 0.f;
            #pragma unroll
            for (int i = 0; i < 16; i++) a += sq[i];
            atomicAdd(l2out, a * (0.01f / 4096.0f));
        }
    }

    if (g2) {
        __syncthreads();
        #pragma unroll
        for (int r = 0; r < 4; r++) {
            float s1 = v[0][r] + v[1][r];
            float s2 = v[0][r]*v[0][r] + v[1][r]*v[1][r];
            s1 = row_sum16(s1); s2 = row_sum16(s2);
            if (lrow == 0) { red[w][quad * 4 + r][0] = s1; red[w][quad * 4 + r][1] = s2; }
        }
        __syncthreads();
        #pragma unroll
        for (int r = 0; r < 4; r++) {
            int rr = quad * 4 + r;
            float t1 = 0.f, t2 = 0.f;
            #pragma unroll
            for (int ww = 0; ww < 8; ww++) { t1 += red[ww][rr][0]; t2 += red[ww][rr][1]; }
            float mu = t1 * (1.0f / 256.0f);
            float var = t2 * (1.0f / 256.0f) - mu * mu;
            float rstd = rsqrtf(var + 1e-5f);
            #pragma unroll
            for (int nj = 0; nj < 2; nj++) {
                int col = w * 32 + nj * 16 + lrow;
                outB[(size_t)(m0 + rr) * 256 + col] = bf16bits((v[nj][r] - mu) * rstd * g2[col] + b2[col]);
            }
        }
    } else if (outB) {
        #pragma unroll
        for (int nj = 0; nj < 2; nj++) {
            int col = w * 32 + nj * 16 + lrow;
            #pragma unroll
            for (int r = 0; r < 4; r++)
                outB[(size_t)(m0 + quad * 4 + r) * 256 + col] = bf16bits(v[nj][r]);
        }
    }

    // ---- fused cls GEMM: logits(16 x 128) = v(16 x 256) @ clsW(128 x 256)^T ----
    if (clsW) {
        #pragma unroll
        for (int nj = 0; nj < 2; nj++) {
            int col = w * 32 + nj * 16 + lrow;
            #pragma unroll
            for (int r = 0; r < 4; r++)
                hb[quad * 4 + r][col] = bf16bits(v[nj][r]);
        }
        __syncthreads();
        f32x4 cacc = {};
        #pragma unroll
        for (int k0 = 0; k0 < 256; k0 += 32) {
            frag8 a = *reinterpret_cast<const frag8*>(&hb[lrow][k0 + quad * 8]);
            frag8 b = *reinterpret_cast<const frag8*>(clsW + (size_t)(w * 16 + lrow) * 256 + k0 + quad * 8);
            cacc = __builtin_amdgcn_mfma_f32_16x16x32_bf16(a, b, cacc, 0, 0, 0);
        }
        int col = w * 16 + lrow;
        float cb = clsB[col];
        #pragma unroll
        for (int r = 0; r < 4; r++)
            clsOut[(size_t)(m0 + quad * 4 + r) * 128 + col] = cacc[r] + cb;
    }
}

// ---------- fused tail: C1 = ybb@W1 + h0; h2 = gelu(C1@W2 + b2); l2 + cls ------
// Replaces the l1 rowgemm + final rowgemm pair: one dispatch, no h0b round-trip.
__global__ __launch_bounds__(512)
void rowgemm2(const unsigned short* __restrict__ A,      // ybb bf16, K1=512
              const unsigned short* __restrict__ W1,     // opw  256x512
              const float* __restrict__ res,             // h0 fp32
              const unsigned short* __restrict__ W2,     // op_w 256x256
              const float* __restrict__ b2,              // op_b
              const unsigned short* __restrict__ clsW,   // cls_w 128x256
              const float* __restrict__ clsB,
              float* __restrict__ clsOut, float* __restrict__ l2out)
{
    __shared__ __align__(16) unsigned short As[16][136];
    __shared__ __align__(16) unsigned short Bs[256][136];
    __shared__ float red[8][16][2];
    __shared__ float sq[16];
    __shared__ __align__(16) unsigned short hb[16][264];

    const int tid = threadIdx.x;
    const int w = tid >> 6, lane = tid & 63;
    const int lrow = lane & 15, quad = lane >> 4;
    const int m0 = blockIdx.x * 16;

    // ---------------- stage 1: K1 = 512 ----------------
    f32x4 acc[2] = {};
    for (int k0 = 0; k0 < 512; k0 += 128) {
        if (tid < 64) {
            int r_ = tid >> 2, c32 = (tid & 3) * 32;
            #pragma unroll
            for (int q = 0; q < 4; q++)
                *reinterpret_cast<float4*>(&As[r_][c32 + q * 8]) =
                    *reinterpret_cast<const float4*>(A + (size_t)(m0 + r_) * 512 + k0 + c32 + q * 8);
        }
        {
            int c32 = (tid & 3) * 32;
            #pragma unroll
            for (int i = 0; i < 2; i++) {
                int n = (tid >> 2) + i * 128;
                #pragma unroll
                for (int q = 0; q < 4; q++)
                    *reinterpret_cast<float4*>(&Bs[n][c32 + q * 8]) =
                        *reinterpret_cast<const float4*>(W1 + (size_t)n * 512 + k0 + c32 + q * 8);
            }
        }
        __syncthreads();
        #pragma unroll
        for (int h = 0; h < 4; h++) {
            frag8 a = *reinterpret_cast<const frag8*>(&As[lrow][h * 32 + quad * 8]);
            #pragma unroll
            for (int nj = 0; nj < 2; nj++) {
                frag8 b = *reinterpret_cast<const frag8*>(&Bs[w * 32 + nj * 16 + lrow][h * 32 + quad * 8]);
                acc[nj] = __builtin_amdgcn_mfma_f32_16x16x32_bf16(a, b, acc[nj], 0, 0, 0);
            }
        }
        __syncthreads();
    }

    // v1 = acc + res  ->  hb (bf16)
    #pragma unroll
    for (int nj = 0; nj < 2; nj++) {
        int col = w * 32 + nj * 16 + lrow;
        #pragma unroll
        for (int r = 0; r < 4; r++) {
            int row = m0 + quad * 4 + r;
            hb[quad * 4 + r][col] = bf16bits(acc[nj][r] + res[(size_t)row * 256 + col]);
        }
    }
    __syncthreads();

    // ---------------- stage 2: K2 = 256, A = hb ----------------
    f32x4 acc2[2] = {};
    for (int k0 = 0; k0 < 256; k0 += 128) {
        {
            int c32 = (tid & 3) * 32;
            #pragma unroll
            for (int i = 0; i < 2; i++) {
                int n = (tid >> 2) + i * 128;
                #pragma unroll
                for (int q = 0; q < 4; q++)
                    *reinterpret_cast<float4*>(&Bs[n][c32 + q * 8]) =
                        *reinterpret_cast<const float4*>(W2 + (size_t)n * 256 + k0 + c32 + q * 8);
            }
        }
        __syncthreads();
        #pragma unroll
        for (int h = 0; h < 4; h++) {
            frag8 a = *reinterpret_cast<const frag8*>(&hb[lrow][k0 + h * 32 + quad * 8]);
            #pragma unroll
            for (int nj = 0; nj < 2; nj++) {
                frag8 b = *reinterpret_cast<const frag8*>(&Bs[w * 32 + nj * 16 + lrow][h * 32 + quad * 8]);
                acc2[nj] = __builtin_amdgcn_mfma_f32_16x16x32_bf16(a, b, acc2[nj], 0, 0, 0);
            }
        }
        __syncthreads();
    }

    float v2[2][4];
    #pragma unroll
    for (int nj = 0; nj < 2; nj++) {
        int col = w * 32 + nj * 16 + lrow;
        #pragma unroll
        for (int r = 0; r < 4; r++)
            v2[nj][r] = gelu_exact(acc2[nj][r] + b2[col]);
    }

    // overwrite hb with h2 (stage-2 reads completed at the loop's final barrier)
    #pragma unroll
    for (int nj = 0; nj < 2; nj++) {
        int col = w * 32 + nj * 16 + lrow;
        #pragma unroll
        for (int r = 0; r < 4; r++)
            hb[quad * 4 + r][col] = bf16bits(v2[nj][r]);
    }

    // ---- l2 partial (barriers here also publish hb for the cls GEMM) ----
    #pragma unroll
    for (int r = 0; r < 4; r++) {
        float s2 = v2[0][r]*v2[0][r] + v2[1][r]*v2[1][r];
        s2 = row_sum16(s2);
        if (lrow == 0) red[w][quad * 4 + r][0] = s2;
    }
    __syncthreads();
    if (tid < 16) {
        float t = 0.f;
        #pragma unroll
        for (int ww = 0; ww < 8; ww++) t += red[ww][tid][0];
        sq[tid] = sqrtf(t);
    }
    __syncthreads();
    if (tid == 0) {
        float a = 0.f;
        #pragma unroll
        for (int i = 0; i < 16; i++) a += sq[i];
        atomicAdd(l2out, a * (0.01f / 4096.0f));
    }

    // ---- cls GEMM: logits(16 x 128) = h2(16 x 256) @ clsW(128 x 256)^T ----
    {
        f32x4 cacc = {};
        #pragma unroll
        for (int k0 = 0; k0 < 256; k0 += 32) {
            frag8 a = *reinterpret_cast<const frag8*>(&hb[lrow][k0 + quad * 8]);
            frag8 b = *reinterpret_cast<const frag8*>(clsW + (size_t)(w * 16 + lrow) * 256 + k0 + quad * 8);
            cacc = __builtin_amdgcn_mfma_f32_16x16x32_bf16(a, b, cacc, 0, 0, 0);
        }
        int col = w * 16 + lrow;
        float cb = clsB[col];
        #pragma unroll
        for (int r = 0; r < 4; r++)
            clsOut[(size_t)(m0 + quad * 4 + r) * 128 + col] = cacc[r] + cb;
    }
}

// ---------------- chunked selective scan (unchanged — control) ------------------
__global__ __launch_bounds__(1024)
void scan_chunked(const float* __restrict__ xdt,
                  const float* __restrict__ dtw, const float* __restrict__ dtb,
                  const float* __restrict__ ucT,
                  const float* __restrict__ BT, const float* __restrict__ CT,
                  const unsigned short* __restrict__ szT,
                  const float* __restrict__ Ac,
                  const float* __restrict__ Dp,
                  unsigned short* __restrict__ y)
{
    __shared__ float aprod_s[16][64];
    __shared__ float sfin_s[16][64];
    __shared__ float sin_w[16][64];
    __shared__ __align__(16) float ylocal[16][64][4];
    __shared__ __align__(16) float dltS[4][1032];
    __shared__ __align__(16) float ucS[4][1032];

    const int j = blockIdx.x;
    const int bid = (j & 7) * 64 + (j >> 3);     // XCD swizzle
    const int b = bid >> 7;
    const int d0 = (bid & 127) * 4;
    const int w = threadIdx.x >> 6;
    const int lane = threadIdx.x & 63;
    const int dsub = lane >> 4, s = lane & 15;
    const int d = d0 + dsub;
    const int t = w * 64 + lane;

    const float Acoef = Ac[d * 16 + s];          // already * log2(e)

    const float4* Bp = reinterpret_cast<const float4*>(BT + ((size_t)(b * 16 + s)) * 1024 + w * 64);
    const float4* Cp = reinterpret_cast<const float4*>(CT + ((size_t)(b * 16 + s)) * 1024 + w * 64);

    // ---- issue long-latency loads first: uc stage, xdt, B/C tile 0, sz ----
    {
        int dd = lane >> 4, tq = (lane & 15) * 4;
        float4 v = *reinterpret_cast<const float4*>(ucT + ((size_t)(b * 512 + d0 + dd)) * 1024 + w * 64 + tq);
        *reinterpret_cast<float4*>(&ucS[dd][w * 64 + tq]) = v;
    }
    const float* xr = xdt + ((size_t)(b * 1024) + t) * 16;
    float4 x0 = *reinterpret_cast<const float4*>(xr + 0);
    float4 x1 = *reinterpret_cast<const float4*>(xr + 4);
    float4 x2 = *reinterpret_cast<const float4*>(xr + 8);
    float4 x3 = *reinterpret_cast<const float4*>(xr + 12);
    float4 B4 = Bp[0], C4 = Cp[0];
    unsigned short szr[4];
    #pragma unroll
    for (int dd = 0; dd < 4; dd++)
        szr[dd] = szT[((size_t)(b * 512 + d0 + dd)) * 1024 + t];

    // ---- front-end: compute dlt for own chunk (lane = t) ----
    #pragma unroll
    for (int dd = 0; dd < 4; dd++) {
        const float* wt = dtw + (size_t)(d0 + dd) * 16;
        float a2 = dtb[d0 + dd]
            + x0.x * wt[0]  + x0.y * wt[1]  + x0.z * wt[2]  + x0.w * wt[3]
            + x1.x * wt[4]  + x1.y * wt[5]  + x1.z * wt[6]  + x1.w * wt[7]
            + x2.x * wt[8]  + x2.y * wt[9]  + x2.z * wt[10] + x2.w * wt[11]
            + x3.x * wt[12] + x3.y * wt[13] + x3.z * wt[14] + x3.w * wt[15];
        dltS[dd][t] = softplus_f(a2);
    }

    // ---- Phase A: local scan (B/C + dt/ut 1-deep prefetch; per-jj y stores) ----
    float st = 0.0f, ap = 1.0f;
    float4 dt4 = *reinterpret_cast<const float4*>(&dltS[dsub][w * 64]);
    float4 ut4 = *reinterpret_cast<const float4*>(&ucS[dsub][w * 64]);
    #pragma unroll
    for (int q = 0; q < 16; q++) {
        float4 nB, nC, ndt, nut;
        if (q < 15) {
            nB = Bp[q + 1]; nC = Cp[q + 1];
            ndt = *reinterpret_cast<const float4*>(&dltS[dsub][w * 64 + (q + 1) * 4]);
            nut = *reinterpret_cast<const float4*>(&ucS[dsub][w * 64 + (q + 1) * 4]);
        }
        const float* dtp = (const float*)&dt4;
        const float* utp = (const float*)&ut4;
        const float* Btp = (const float*)&B4;
        const float* Ctp = (const float*)&C4;
        #pragma unroll
        for (int jj = 0; jj < 4; jj++) {
            float dA = exp2_raw(dtp[jj] * Acoef);
            st = st * dA + dtp[jj] * utp[jj] * Btp[jj];
            ap *= dA;
            float part = row_sum16(st * Ctp[jj]);
            if (s == 0) ylocal[w][q * 4 + jj][dsub] = part;
        }
        B4 = nB; C4 = nC; dt4 = ndt; ut4 = nut;
    }
    aprod_s[w][lane] = ap;
    sfin_s[w][lane] = st;
    __syncthreads();                                 // the only barrier

    // ---- decentralized combine ----
    {
        float pre = 0.0f;
        #pragma unroll
        for (int c = 0; c < 15; c++) {
            float apc = aprod_s[c][lane];
            float sfc = sfin_s[c][lane];
            float cand = sfc + apc * pre;
            pre = (c < w) ? cand : pre;
        }
        sin_w[w][lane] = pre;
    }

    // ---- Phase C: lane = t; correction via prefix sums + epilogue ----
    float cums[4];
    #pragma unroll
    for (int dd = 0; dd < 4; dd++)
        cums[dd] = dltS[dd][t];
    #pragma unroll
    for (int dd = 0; dd < 4; dd++)
        cums[dd] = prefix_sum64(cums[dd]);

    float4 yl = *reinterpret_cast<const float4*>(&ylocal[w][lane][0]);
    float acc[4] = { yl.x, yl.y, yl.z, yl.w };

    float Cs[4];
    #pragma unroll
    for (int jj = 0; jj < 4; jj++)
        Cs[jj] = CT[((size_t)(b * 16 + jj)) * 1024 + t];
    #pragma unroll
    for (int sq = 0; sq < 4; sq++) {
        float Csn[4];
        if (sq < 3) {
            #pragma unroll
            for (int jj = 0; jj < 4; jj++)
                Csn[jj] = CT[((size_t)(b * 16 + (sq + 1) * 4 + jj)) * 1024 + t];
        }
        #pragma unroll
        for (int dd = 0; dd < 4; dd++) {
            float4 sin4 = *reinterpret_cast<const float4*>(&sin_w[w][dd * 16 + sq * 4]);
            const float* sp = (const float*)&sin4;
            #pragma unroll
            for (int jj = 0; jj < 4; jj++) {
                float ac = Ac[(d0 + dd) * 16 + sq * 4 + jj];      // already * log2(e)
                acc[dd] += sp[jj] * Cs[jj] * exp2_raw(ac * cums[dd]);
            }
        }
        #pragma unroll
        for (int jj = 0; jj < 4; jj++) Cs[jj] = Csn[jj];
    }

    const size_t row = (size_t)b * 1024 + t;
    ushort4 yo;
    {
        float ut0 = ucS[0][t], ut1 = ucS[1][t], ut2 = ucS[2][t], ut3 = ucS[3][t];
        float y0 = (acc[0] + ut0 * Dp[d0 + 0]) * bf2f(szr[0]);
        float y1 = (acc[1] + ut1 * Dp[d0 + 1]) * bf2f(szr[1]);
        float y2 = (acc[2] + ut2 * Dp[d0 + 2]) * bf2f(szr[2]);
        float y3 = (acc[3] + ut3 * Dp[d0 + 3]) * bf2f(szr[3]);
        yo.x = bf16bits(y0); yo.y = bf16bits(y1);
        yo.z = bf16bits(y2); yo.w = bf16bits(y3);
    }
    *reinterpret_cast<ushort4*>(y + row * 512 + d0) = yo;
}

// ---------------- launcher ----------------
extern "C" void kernel_launch(void* const* d_in, const int* in_sizes, int n_in,
                              void* d_out, int out_size, void* d_ws, size_t ws_size,
                              hipStream_t stream)
{
    const float* x      = (const float*)d_in[0];
    const float* in_b   = (const float*)d_in[2];
    const float* ln_g   = (const float*)d_in[3];
    const float* ln_b   = (const float*)d_in[4];
    const float* blk_ng  = (const float*)d_in[5];
    const float* blk_nb  = (const float*)d_in[6];
    const float* blk_cw  = (const float*)d_in[8];
    const float* blk_cb  = (const float*)d_in[9];
    const float* blk_dtw = (const float*)d_in[11];
    const float* blk_dtb = (const float*)d_in[12];
    const float* blk_Alog= (const float*)d_in[13];
    const float* blk_D   = (const float*)d_in[14];
    const float* op_b   = (const float*)d_in[17];
    const float* cls_b  = (const float*)d_in[19];
    float* out = (float*)d_out;

    const int BL = 4096;
    float* ws = (float*)d_ws;
    float* h0   = ws;                         // 1,048,576
    float* xzuT = h0 + 1048576;               // 2,097,152  [b][d][t] fp32 (u pre-conv)
    float* ucT  = xzuT + 2097152;             // 2,097,152  [b][d][t]
    float* xdt  = ucT + 2097152;              // 131,072 (2 layers x 4096x16)
    float* BT   = xdt + 131072;               // 131,072 (2 layers x [b][s][t])
    float* CT   = BT + 131072;                // 131,072
    float* Ac   = CT + 131072;                // 16,384
    unsigned short* szT = (unsigned short*)(Ac + 16384);  // 2,097,152 bf16 [b][d][t]
    unsigned short* wb  = szT + 2097152;      // 1,130,496
    unsigned short* hnb = wb + 1130496;       // 1,048,576
    unsigned short* ybb = hnb + 1048576;      // 2,097,152
    unsigned short* in_wb  = wb;
    unsigned short* ipw_b  = wb + 196608;
    unsigned short* xpw_b  = wb + 720896;
    unsigned short* opw_b  = wb + 770048;
    unsigned short* op_wb  = wb + 1032192;
    unsigned short* cls_wb = wb + 1097728;

    CvtArgs ca;
    ca.src[0] = (const float*)d_in[1];  ca.dst[0] = in_wb;  ca.n4[0] = 196608 / 4;
    ca.src[1] = (const float*)d_in[7];  ca.dst[1] = ipw_b;  ca.n4[1] = 524288 / 4;
    ca.src[2] = (const float*)d_in[10]; ca.dst[2] = xpw_b;  ca.n4[2] = 49152 / 4;
    ca.src[3] = (const float*)d_in[15]; ca.dst[3] = opw_b;  ca.n4[3] = 262144 / 4;
    ca.src[4] = (const float*)d_in[16]; ca.dst[4] = op_wb;  ca.n4[4] = 65536 / 4;
    ca.src[5] = (const float*)d_in[18]; ca.dst[5] = cls_wb; ca.n4[5] = 32768 / 4;
    int total4 = 1130496 / 4;
    int zquads = 393216 / 4;                  // xdt+BT+CT (both layers, contiguous)
    int totalg = total4 + 16384 + zquads;
    cvt_all<<<(totalg + 255) / 256, 256, 0, stream>>>(ca, total4, blk_Alog, Ac,
                                                      xdt, zquads,
                                                      out + (size_t)BL * 128);

    // in_proj (A from fp32 x) + bias + LN + GELU -> h0 (fp32), + LN(layer0) -> hnb
    rowgemm<<<256, 512, 0, stream>>>(nullptr, x, in_wb, in_b, nullptr,
                                     ln_g, ln_b, 1,
                                     blk_ng, blk_nb,
                                     h0, hnb, nullptr,
                                     nullptr, nullptr, nullptr, 768);

    for (int l = 0; l < 2; l++) {
        const float* cw   = blk_cw  + (size_t)l * 512 * 4;
        const float* cb   = blk_cb  + l * 512;
        const float* dtw  = blk_dtw + (size_t)l * 512 * 16;
        const float* dtb  = blk_dtb + l * 512;
        const float* Dl   = blk_D   + l * 512;
        const unsigned short* ipwl = ipw_b + (size_t)l * 262144;
        const unsigned short* xpwl = xpw_b + (size_t)l * 24576;
        const unsigned short* opwl = opw_b + (size_t)l * 131072;
        float* xdtl = xdt + (size_t)l * 65536;
        float* BTl  = BT  + (size_t)l * 65536;
        float* CTl  = CT  + (size_t)l * 65536;

        // ipw GEMM: u -> xzuT fp32 [b][d][t]; z -> silu(z) bf16 szT [b][d][t]
        gemm_ipw<<<dim3(16, 64), 256, 0, stream>>>(hnb, ipwl, xzuT, szT);
        // fused conv + xpw projection (K-split x4): ucT + atomic xdt/BT/CT
        gemm_cat<<<dim3(4, 64), 256, 0, stream>>>(xzuT, xpwl, cw, cb, ucT, xdtl, BTl, CTl);
        // scan (computes dlt from xdt in-kernel) -> ybb
        scan_chunked<<<512, 1024, 0, stream>>>(xdtl, dtw, dtb, ucT, BTl, CTl, szT,
                                               Ac + (size_t)l * 8192, Dl, ybb);
        // layer0: h0 += ybb @ opw.T, + LN(layer1) -> hnb
        // layer1: fused into rowgemm2 below (no h0b round-trip)
        if (l == 0)
            rowgemm<<<256, 512, 0, stream>>>(ybb, nullptr, opwl, nullptr, h0,
                                             nullptr, nullptr, 0,
                                             blk_ng + 256, blk_nb + 256,
                                             h0, hnb, nullptr,
                                             nullptr, nullptr, nullptr, 512);
        else
            rowgemm2<<<256, 512, 0, stream>>>(ybb, opwl, h0,
                                              op_wb, op_b,
                                              cls_wb, cls_b,
                                              out, out + (size_t)BL * 128);
    }
}